// Round 1
// 2139.078 us; speedup vs baseline: 2.3849x; 2.3849x over previous
//
#include <hip/hip_runtime.h>
#include <hip/hip_bf16.h>
#include <math.h>

// Problem constants
#define B_    8
#define N1_   4096
#define N2_   4096
#define C_    512
#define P_    256
#define H_    8
#define MLP_  2048
#define HD_   64

typedef __hip_bfloat16 bf16;
typedef __attribute__((ext_vector_type(8))) short short8;   // 8 bf16 (4 VGPRs)
typedef __attribute__((ext_vector_type(4))) float f32x4;

__device__ __forceinline__ float bf2f(bf16 v) { return __bfloat162float(v); }
__device__ __forceinline__ bf16  f2bf(float v) { return __float2bfloat16(v); }
__device__ __forceinline__ float ubf2f(unsigned short u) {
  union { float f; unsigned int i; } cv; cv.i = ((unsigned int)u) << 16; return cv.f;
}
__device__ __forceinline__ unsigned short f2bfu(float v) {
  union { bf16 b; unsigned short u; } cv; cv.b = __float2bfloat16(v); return cv.u;
}
__device__ __forceinline__ float gelu_exact(float x) {
  return 0.5f * x * (1.0f + erff(x * 0.70710678118654752f));
}

// async global->LDS, 16B per lane (global_load_lds_dwordx4)
__device__ __forceinline__ void gload16(const void* g, void* l) {
  __builtin_amdgcn_global_load_lds(
      (const __attribute__((address_space(1))) void*)g,
      (__attribute__((address_space(3))) void*)l, 16, 0, 0);
}

// ---------------------------------------------------------------------------
// f32 -> bf16 elementwise (x1/x2 conversion). n4 = count/4.
__global__ __launch_bounds__(256) void f2b_kernel(
    const float* __restrict__ in, bf16* __restrict__ out, int n4)
{
  int i = blockIdx.x * 256 + threadIdx.x;
  const int stride = gridDim.x * 256;
  for (; i < n4; i += stride) {
    const float4 v = ((const float4*)in)[i];
    ushort4 o;
    o.x = f2bfu(v.x); o.y = f2bfu(v.y); o.z = f2bfu(v.z); o.w = f2bfu(v.w);
    ((ushort4*)out)[i] = o;
  }
}

// f32 (K,N) row-major (leading dim ldin) -> bf16 (N,K) transposed.
// 32x32 LDS tile, both sides coalesced. K,N multiples of 32.
__global__ __launch_bounds__(256) void transpose_f2b_kernel(
    const float* __restrict__ in, bf16* __restrict__ out, int K, int N, int ldin)
{
  __shared__ float tile[32][33];
  const int kb = blockIdx.y * 32, nb = blockIdx.x * 32;
  const int tx = threadIdx.x & 31, ty = threadIdx.x >> 5;  // ty = 0..7
  #pragma unroll
  for (int i = 0; i < 4; ++i)
    tile[ty + 8 * i][tx] = in[(size_t)(kb + ty + 8 * i) * ldin + nb + tx];
  __syncthreads();
  #pragma unroll
  for (int i = 0; i < 4; ++i)
    out[(size_t)(nb + ty + 8 * i) * K + kb + tx] = f2bf(tile[tx][ty + 8 * i]);
}

// ---------------------------------------------------------------------------
// MFMA bf16 GEMM (m97 structure): C = A @ Bt^T (+bias +pos, opt gelu).
// A: (M,K) bf16 row-major. Bt: (N,K) bf16 row-major (pre-transposed weights).
// Tile BM=128 x BN (128 or 64), BK=32, 256 threads = 4 waves.
// BN=128: wave grid 2x2, 4x4 fragments/wave. BN=64: 4x1 waves, 2x4 fragments.
// Staging via global_load_lds width 16 (linear LDS [row][k], 64B rows);
// fragments via ds_read_b128; 16x16x32 bf16 MFMA, f32 accum.
template<int BN, int OUTF32, int ACT, int POS>
__global__ __launch_bounds__(256) void mfma_gemm_kernel(
    const bf16* __restrict__ A, const bf16* __restrict__ Bt,
    const float* __restrict__ bias, const float* __restrict__ pos, int posmask,
    void* __restrict__ Cv, int M, int N, int K)
{
  constexpr int WGN = BN / 64;            // wave-grid cols (2 or 1)
  constexpr int WGR = 4 / WGN;            // wave-grid rows (2 or 4)
  constexpr int FM  = 128 / (16 * WGR);   // A fragments per wave (4 or 2)
  __shared__ bf16 As[128 * 32];           // [m][k], row = 64B
  __shared__ bf16 Bs[BN * 32];            // [n][k]
  const int t  = threadIdx.x;
  const int l  = t & 63;
  const int w  = t >> 6;
  const int wr = w / WGN, wc = w % WGN;
  const int lr = l & 15, kg = l >> 4;
  const int m0 = blockIdx.y * 128, n0 = blockIdx.x * BN;

  // staging: thread t -> row t/4 (and +64), k-offset (t&3)*8
  const bf16* ga = A  + (size_t)(m0 + (t >> 2)) * K + (t & 3) * 8;
  const bf16* gb = Bt + (size_t)(n0 + (t >> 2)) * K + (t & 3) * 8;
  char* asl = (char*)As + t * 16;
  char* bsl = (char*)Bs + t * 16;

  f32x4 acc[FM][4] = {};

  for (int k0 = 0; k0 < K; k0 += 32) {
    gload16(ga, asl);
    gload16(ga + (size_t)64 * K, asl + 4096);
    gload16(gb, bsl);
    if (BN == 128) gload16(gb + (size_t)64 * K, bsl + 4096);
    ga += 32; gb += 32;
    __syncthreads();            // compiler emits vmcnt(0) drain before barrier
    short8 af[FM], bfv[4];
    #pragma unroll
    for (int i = 0; i < FM; ++i)
      af[i] = *(const short8*)&As[(wr * (FM * 16) + i * 16 + lr) * 32 + kg * 8];
    #pragma unroll
    for (int j = 0; j < 4; ++j)
      bfv[j] = *(const short8*)&Bs[(wc * 64 + j * 16 + lr) * 32 + kg * 8];
    #pragma unroll
    for (int i = 0; i < FM; ++i)
      #pragma unroll
      for (int j = 0; j < 4; ++j)
        acc[i][j] = __builtin_amdgcn_mfma_f32_16x16x32_bf16(
            af[i], bfv[j], acc[i][j], 0, 0, 0);
    __syncthreads();
  }

  // epilogue: D frag layout col = lane&15, row = (lane>>4)*4 + r
  #pragma unroll
  for (int i = 0; i < FM; ++i) {
    #pragma unroll
    for (int j = 0; j < 4; ++j) {
      const int n = n0 + wc * 64 + j * 16 + lr;
      const float bv = bias[n];
      #pragma unroll
      for (int r = 0; r < 4; ++r) {
        const int m = m0 + wr * (FM * 16) + i * 16 + kg * 4 + r;
        float v = acc[i][j][r] + bv;
        if (POS) v += pos[(size_t)(m & posmask) * N + n];
        if (ACT) v = gelu_exact(v);
        if (OUTF32) ((float*)Cv)[(size_t)m * N + n] = v;
        else        ((bf16*)Cv)[(size_t)m * N + n] = f2bf(v);
      }
    }
  }
}

// ---------------------------------------------------------------------------
// Legacy VALU GEMM — retained ONLY for the TRANSA kp/vp einsum path
// (A bf16 in (K,M) layout, K=4096 contraction over rows). MFMA-izing this
// needs a transpose-staging step; next round.
template<int TRANSA, int AF32, int OUTF32, int ACT>
__global__ __launch_bounds__(256) void gemm_kernel(
    const void* __restrict__ A, const float* __restrict__ Bm,
    const float* __restrict__ bias, const float* __restrict__ pos, int posmask,
    void* __restrict__ Cv, int M, int N, int K, int lda, int ldb,
    long aOuter, int aInnerCnt, int aInner, long cBatch)
{
  __shared__ float As[16][65];
  __shared__ float Bs[16][65];
  const int z = blockIdx.z;
  const long aoff = (long)(z / aInnerCnt) * aOuter + (long)(z % aInnerCnt) * aInner;
  const int n0 = blockIdx.x * 64;
  const int m0 = blockIdx.y * 64;
  const int t  = threadIdx.x;
  const int tx = t & 15, ty = t >> 4;
  float acc[4][4] = {};
  for (int k0 = 0; k0 < K; k0 += 16) {
    if (TRANSA) {   // bf16 A, (K,M) layout
      const bf16* Ab = (const bf16*)A + aoff;
      const int mm = t & 63, kk = t >> 6;
      #pragma unroll
      for (int i = 0; i < 4; ++i)
        As[kk + 4*i][mm] = bf2f(Ab[(size_t)(k0 + kk + 4*i) * lda + m0 + mm]);
    } else if (AF32) {
      const float* Ab = (const float*)A + aoff;
      const int mm = t >> 2, kk4 = (t & 3) * 4;
      const float4 av = *(const float4*)(Ab + (size_t)(m0 + mm) * lda + k0 + kk4);
      As[kk4+0][mm] = av.x;
      As[kk4+1][mm] = av.y;
      As[kk4+2][mm] = av.z;
      As[kk4+3][mm] = av.w;
    } else {
      const bf16* Ab = (const bf16*)A + aoff;
      const int mm = t >> 2, kk4 = (t & 3) * 4;
      const ushort4 av = *(const ushort4*)(Ab + (size_t)(m0 + mm) * lda + k0 + kk4);
      As[kk4+0][mm] = ubf2f(av.x);
      As[kk4+1][mm] = ubf2f(av.y);
      As[kk4+2][mm] = ubf2f(av.z);
      As[kk4+3][mm] = ubf2f(av.w);
    }
    {
      const int nn = t & 63, kk = t >> 6;
      #pragma unroll
      for (int i = 0; i < 4; ++i)
        Bs[kk + 4*i][nn] = Bm[(size_t)(k0 + kk + 4*i) * ldb + n0 + nn];
    }
    __syncthreads();
    #pragma unroll
    for (int kk = 0; kk < 16; ++kk) {
      float a[4], bb[4];
      #pragma unroll
      for (int i = 0; i < 4; ++i) a[i]  = As[kk][ty + 16*i];
      #pragma unroll
      for (int j = 0; j < 4; ++j) bb[j] = Bs[kk][tx + 16*j];
      #pragma unroll
      for (int i = 0; i < 4; ++i)
        #pragma unroll
        for (int j = 0; j < 4; ++j)
          acc[i][j] += a[i] * bb[j];
    }
    __syncthreads();
  }
  const long coff = (long)z * cBatch;
  #pragma unroll
  for (int i = 0; i < 4; ++i) {
    const int m = m0 + ty + 16*i;
    #pragma unroll
    for (int j = 0; j < 4; ++j) {
      const int n = n0 + tx + 16*j;
      float v = acc[i][j];
      if (bias) v += bias[n];
      if (pos)  v += pos[(size_t)(m & posmask) * N + n];
      if (ACT)  v = gelu_exact(v);
      if (OUTF32) ((float*)Cv)[coff + (size_t)m * N + n] = v;
      else        ((bf16*)Cv)[coff + (size_t)m * N + n] = f2bf(v);
    }
  }
}

// ---------------------------------------------------------------------------
// Fused attention (unchanged this round — next optimization target).
__global__ __launch_bounds__(256) void attn_kernel(
    const bf16* __restrict__ qb, const float* __restrict__ kp,
    const float* __restrict__ vp, const float* __restrict__ temp,
    bf16* __restrict__ xat)
{
  __shared__ float u[16640];                 // kpl[64][256] | vpl[256][65]
  __shared__ float shqT[64][20];             // q-tile transposed [d][row]
  __shared__ unsigned short shp[16][256];    // softmaxed P, bf16
  const int t = threadIdx.x;
  const int w = t >> 6, l = t & 63;
  const int b = blockIdx.z, h = blockIdx.y;
  const int q0 = blockIdx.x * 16;
  const float* kpb = kp + ((size_t)(b * H_ + h)) * HD_ * P_;
  const float* vpb = vp + ((size_t)(b * H_ + h)) * HD_ * P_;

  #pragma unroll
  for (int i = 0; i < 4; ++i) {
    const int lr = w + 4 * i;
    shqT[l][lr] = bf2f(qb[((size_t)(b * N1_ + q0 + lr)) * C_ + h * HD_ + l]);
  }
  {
    float4* dst = (float4*)u;
    const float4* src = (const float4*)kpb;
    #pragma unroll
    for (int i = 0; i < 16; ++i) dst[i * 256 + t] = src[i * 256 + t];
  }
  __syncthreads();

  float s[4][4] = {};
  #pragma unroll 4
  for (int d = 0; d < 64; ++d) {
    const float4 kv = *(const float4*)&u[d * 256 + 4 * l];
    const float4 qv = *(const float4*)&shqT[d][4 * w];
    s[0][0] += qv.x * kv.x; s[0][1] += qv.x * kv.y; s[0][2] += qv.x * kv.z; s[0][3] += qv.x * kv.w;
    s[1][0] += qv.y * kv.x; s[1][1] += qv.y * kv.y; s[1][2] += qv.y * kv.z; s[1][3] += qv.y * kv.w;
    s[2][0] += qv.z * kv.x; s[2][1] += qv.z * kv.y; s[2][2] += qv.z * kv.z; s[2][3] += qv.z * kv.w;
    s[3][0] += qv.w * kv.x; s[3][1] += qv.w * kv.y; s[3][2] += qv.w * kv.z; s[3][3] += qv.w * kv.w;
  }
  const float tv = temp[h];
  #pragma unroll
  for (int ri = 0; ri < 4; ++ri) {
    float a0 = s[ri][0] * tv, a1 = s[ri][1] * tv;
    float a2 = s[ri][2] * tv, a3 = s[ri][3] * tv;
    float m = fmaxf(fmaxf(a0, a1), fmaxf(a2, a3));
    #pragma unroll
    for (int off = 32; off > 0; off >>= 1) m = fmaxf(m, __shfl_xor(m, off));
    const float e0 = __expf(a0 - m), e1 = __expf(a1 - m);
    const float e2 = __expf(a2 - m), e3 = __expf(a3 - m);
    float sm = e0 + e1 + e2 + e3;
    #pragma unroll
    for (int off = 32; off > 0; off >>= 1) sm += __shfl_xor(sm, off);
    const float inv = 1.0f / sm;
    ushort4 pk;
    pk.x = f2bfu(e0 * inv); pk.y = f2bfu(e1 * inv);
    pk.z = f2bfu(e2 * inv); pk.w = f2bfu(e3 * inv);
    *(ushort4*)&shp[4 * w + ri][4 * l] = pk;
  }
  __syncthreads();

  #pragma unroll
  for (int i = 0; i < 16; ++i) {
    const int d = i * 4 + w;
    const float* vr = vpb + d * P_;
    u[(l      ) * 65 + d] = vr[l      ];
    u[(l +  64) * 65 + d] = vr[l +  64];
    u[(l + 128) * 65 + d] = vr[l + 128];
    u[(l + 192) * 65 + d] = vr[l + 192];
  }
  __syncthreads();

  float o[4] = {0.f, 0.f, 0.f, 0.f};
  #pragma unroll 4
  for (int g = 0; g < 64; ++g) {
    const float v0 = u[(4 * g + 0) * 65 + l];
    const float v1 = u[(4 * g + 1) * 65 + l];
    const float v2 = u[(4 * g + 2) * 65 + l];
    const float v3 = u[(4 * g + 3) * 65 + l];
    #pragma unroll
    for (int ri = 0; ri < 4; ++ri) {
      const ushort4 pw = *(const ushort4*)&shp[4 * w + ri][4 * g];
      o[ri] += ubf2f(pw.x) * v0 + ubf2f(pw.y) * v1
             + ubf2f(pw.z) * v2 + ubf2f(pw.w) * v3;
    }
  }
  const size_t rbase = (size_t)(b * H_ + h) * N1_ + q0 + 4 * w;
  #pragma unroll
  for (int ri = 0; ri < 4; ++ri)
    xat[(rbase + ri) * HD_ + l] = f2bf(o[ri]);
}

__global__ __launch_bounds__(256) void norm1_kernel(
    const bf16* __restrict__ xat, const bf16* __restrict__ qb,
    bf16* __restrict__ xb)
{
  const int row = blockIdx.x;
  const int b = row >> 12, np = row & 4095;
  const int d = np >> 6, h = (np >> 3) & 7, qhi = np & 7;
  const int c0 = threadIdx.x, c1 = threadIdx.x + 256;
  const size_t sbase = (size_t)((b * H_ + h) * N1_ + qhi * 512);
  float v0 = bf2f(xat[(sbase + c0) * HD_ + d]) + bf2f(qb[(size_t)row * C_ + c0]);
  float v1 = bf2f(xat[(sbase + c1) * HD_ + d]) + bf2f(qb[(size_t)row * C_ + c1]);
  float ss = v0 * v0 + v1 * v1;
  #pragma unroll
  for (int off = 32; off > 0; off >>= 1) ss += __shfl_xor(ss, off);
  __shared__ float sw[4];
  if ((threadIdx.x & 63) == 0) sw[threadIdx.x >> 6] = ss;
  __syncthreads();
  const float tot = sw[0] + sw[1] + sw[2] + sw[3];
  const float scale = 1.0f / fmaxf(sqrtf(tot), 1e-12f);
  xb[(size_t)row * C_ + c0] = f2bf(v0 * scale);
  xb[(size_t)row * C_ + c1] = f2bf(v1 * scale);
}

__global__ __launch_bounds__(256) void norm2_kernel(
    const float* __restrict__ yb, const bf16* __restrict__ xb,
    float* __restrict__ outp)
{
  const int row = blockIdx.x;
  const int c0 = threadIdx.x, c1 = threadIdx.x + 256;
  float v0 = yb[(size_t)row * C_ + c0] + bf2f(xb[(size_t)row * C_ + c0]);
  float v1 = yb[(size_t)row * C_ + c1] + bf2f(xb[(size_t)row * C_ + c1]);
  float ss = v0 * v0 + v1 * v1;
  #pragma unroll
  for (int off = 32; off > 0; off >>= 1) ss += __shfl_xor(ss, off);
  __shared__ float sw[4];
  if ((threadIdx.x & 63) == 0) sw[threadIdx.x >> 6] = ss;
  __syncthreads();
  const float tot = sw[0] + sw[1] + sw[2] + sw[3];
  const float scale = 1.0f / fmaxf(sqrtf(tot), 1e-12f);
  outp[(size_t)row * C_ + c0] = v0 * scale;
  outp[(size_t)row * C_ + c1] = v1 * scale;
}

// ---------------------------------------------------------------------------
extern "C" void kernel_launch(void* const* d_in, const int* in_sizes, int n_in,
                              void* d_out, int out_size, void* d_ws, size_t ws_size,
                              hipStream_t stream)
{
  const float* x1   = (const float*)d_in[0];
  const float* x2   = (const float*)d_in[1];
  const float* Wq   = (const float*)d_in[2];
  const float* bq   = (const float*)d_in[3];
  const float* Wkv  = (const float*)d_in[4];
  const float* bkv  = (const float*)d_in[5];
  const float* Wp   = (const float*)d_in[6];
  const float* bp   = (const float*)d_in[7];
  const float* posq = (const float*)d_in[8];
  const float* posk = (const float*)d_in[9];
  const float* temp = (const float*)d_in[10];
  const float* W1   = (const float*)d_in[11];
  const float* b1   = (const float*)d_in[12];
  const float* W2   = (const float*)d_in[13];
  const float* b2   = (const float*)d_in[14];

  // Workspace (peak 120 MiB), region lifetimes:
  //  A [0,32M):    x2b -> x1b -> xb
  //  B [32,64M):   kb -> vb -> xat -> hb
  //  C [64,96M):   qb
  //  [96,100M):    kp -> (W1t@96M, W2t@98M after attn)
  //  [100,104M):   vp
  //  [104,120M):   Wqt@104M, Wkt@104.5M, Wvt@105M -> yb (16 MiB, MLP phase)
  char* ws = (char*)d_ws;
  bf16*  Abuf = (bf16*) (ws);
  bf16*  Bbuf = (bf16*) (ws + 33554432);
  bf16*  qb   = (bf16*) (ws + 67108864);
  float* kp   = (float*)(ws + 100663296);
  float* vp   = (float*)(ws + 104857600);
  bf16*  W1t  = (bf16*) (ws + 100663296);   // aliases kp (dead after attn)
  bf16*  W2t  = (bf16*) (ws + 102760448);
  bf16*  Wqt  = (bf16*) (ws + 109051904);
  bf16*  Wkt  = (bf16*) (ws + 109576192);
  bf16*  Wvt  = (bf16*) (ws + 110100480);
  float* yb   = (float*)(ws + 109051904);   // aliases Wq/Wk/Wv_t (dead in MLP)
  float* outp = (float*)d_out;

  const dim3 blk(256);
  const int Mrows = B_ * N1_;       // 32768
  const int CH = 8192;              // MLP row-chunk (hb = 32 MiB, yb = 16 MiB)
  bf16* xat = Bbuf;
  bf16* xb  = Abuf;
  bf16* hb  = Bbuf;

  // x2 -> bf16
  f2b_kernel<<<dim3(2048), blk, 0, stream>>>(x2, Abuf, (B_ * N2_ * C_) / 4);
  // weight transposes (f32 (K,N) -> bf16 (N,K)) for the MFMA B^T layout
  transpose_f2b_kernel<<<dim3(16, 16), blk, 0, stream>>>(Wkv,      Wkt, C_, C_, 2 * C_);
  transpose_f2b_kernel<<<dim3(16, 16), blk, 0, stream>>>(Wkv + C_, Wvt, C_, C_, 2 * C_);
  transpose_f2b_kernel<<<dim3(16, 16), blk, 0, stream>>>(Wq,       Wqt, C_, C_, C_);

  // k = x2@Wkv[:, :C] + bkv[:C] + pos_k   (MFMA, bf16 out)
  mfma_gemm_kernel<128,0,0,1><<<dim3(C_/128, Mrows/128), blk, 0, stream>>>(
      Abuf, Wkt, bkv, posk, N2_ - 1, Bbuf, Mrows, C_, C_);
  // kp[b,h,d,p] = sum_n k[b,n,h*64+d]*Wp[n,p] + bp   (legacy VALU TRANSA)
  gemm_kernel<1,0,1,0><<<dim3(P_/64, HD_/64, B_*H_), blk, 0, stream>>>(
      Bbuf, Wp, bp, nullptr, 0, kp, HD_, P_, N2_, C_, P_,
      (long)N2_*C_, H_, HD_, (long)HD_*P_);
  // v = x2@Wkv[:, C:] + bkv[C:]   (overwrites kb — dead after kp)
  mfma_gemm_kernel<128,0,0,0><<<dim3(C_/128, Mrows/128), blk, 0, stream>>>(
      Abuf, Wvt, bkv + C_, nullptr, 0, Bbuf, Mrows, C_, C_);
  // vp
  gemm_kernel<1,0,1,0><<<dim3(P_/64, HD_/64, B_*H_), blk, 0, stream>>>(
      Bbuf, Wp, bp, nullptr, 0, vp, HD_, P_, N2_, C_, P_,
      (long)N2_*C_, H_, HD_, (long)HD_*P_);
  // x1 -> bf16 (x2b dead)
  f2b_kernel<<<dim3(2048), blk, 0, stream>>>(x1, Abuf, (B_ * N1_ * C_) / 4);
  // q = x1@Wq + bq + pos_q
  mfma_gemm_kernel<128,0,0,1><<<dim3(C_/128, Mrows/128), blk, 0, stream>>>(
      Abuf, Wqt, bq, posq, N1_ - 1, qb, Mrows, C_, C_);
  // fused attention -> xat (natural layout, region B; vb dead)
  attn_kernel<<<dim3(N1_/16, H_, B_), blk, 0, stream>>>(qb, kp, vp, temp, xat);
  // MLP weight transposes into kp region (kp/vp dead after attn)
  transpose_f2b_kernel<<<dim3(64, 16), blk, 0, stream>>>(W1, W1t, C_,   MLP_, MLP_);
  transpose_f2b_kernel<<<dim3(16, 64), blk, 0, stream>>>(W2, W2t, MLP_, C_,   C_);
  // x = l2norm(scramble(attn) + q) -> region A (x1b dead)
  norm1_kernel<<<dim3(Mrows), blk, 0, stream>>>(xat, qb, xb);
  // MLP + final norm, chunked
  for (int c = 0; c < Mrows / CH; ++c) {
    const bf16* xc = xb + (size_t)c * CH * C_;
    mfma_gemm_kernel<128,0,1,0><<<dim3(MLP_/128, CH/128), blk, 0, stream>>>(
        xc, W1t, b1, nullptr, 0, hb, CH, MLP_, C_);
    mfma_gemm_kernel<64,1,0,0><<<dim3(C_/64, CH/128), blk, 0, stream>>>(
        hb, W2t, b2, nullptr, 0, yb, CH, C_, MLP_);
    norm2_kernel<<<dim3(CH), blk, 0, stream>>>(
        yb, xc, outp + (size_t)c * CH * C_);
  }
}

// Round 2
// 933.820 us; speedup vs baseline: 5.4631x; 2.2907x over previous
//
#include <hip/hip_runtime.h>
#include <hip/hip_bf16.h>
#include <math.h>

// Problem constants
#define B_    8
#define N1_   4096
#define N2_   4096
#define C_    512
#define P_    256
#define H_    8
#define MLP_  2048
#define HD_   64

typedef __hip_bfloat16 bf16;
typedef __attribute__((ext_vector_type(8))) short short8;   // 8 bf16 (4 VGPRs)
typedef __attribute__((ext_vector_type(4))) float f32x4;

__device__ __forceinline__ float bf2f(bf16 v) { return __bfloat162float(v); }
__device__ __forceinline__ bf16  f2bf(float v) { return __float2bfloat16(v); }
__device__ __forceinline__ float ubf2f(unsigned short u) {
  union { float f; unsigned int i; } cv; cv.i = ((unsigned int)u) << 16; return cv.f;
}
__device__ __forceinline__ unsigned short f2bfu(float v) {
  union { bf16 b; unsigned short u; } cv; cv.b = __float2bfloat16(v); return cv.u;
}
__device__ __forceinline__ float gelu_exact(float x) {
  return 0.5f * x * (1.0f + erff(x * 0.70710678118654752f));
}

// async global->LDS, 16B per lane (global_load_lds_dwordx4)
__device__ __forceinline__ void gload16(const void* g, void* l) {
  __builtin_amdgcn_global_load_lds(
      (const __attribute__((address_space(1))) void*)g,
      (__attribute__((address_space(3))) void*)l, 16, 0, 0);
}

// ---------------------------------------------------------------------------
// f32 -> bf16 elementwise (x1/x2 conversion). n4 = count/4.
__global__ __launch_bounds__(256) void f2b_kernel(
    const float* __restrict__ in, bf16* __restrict__ out, int n4)
{
  int i = blockIdx.x * 256 + threadIdx.x;
  const int stride = gridDim.x * 256;
  for (; i < n4; i += stride) {
    const float4 v = ((const float4*)in)[i];
    ushort4 o;
    o.x = f2bfu(v.x); o.y = f2bfu(v.y); o.z = f2bfu(v.z); o.w = f2bfu(v.w);
    ((ushort4*)out)[i] = o;
  }
}

// f32 (K,N) row-major (leading dim ldin) -> bf16 (N,K) transposed.
__global__ __launch_bounds__(256) void transpose_f2b_kernel(
    const float* __restrict__ in, bf16* __restrict__ out, int K, int N, int ldin)
{
  __shared__ float tile[32][33];
  const int kb = blockIdx.y * 32, nb = blockIdx.x * 32;
  const int tx = threadIdx.x & 31, ty = threadIdx.x >> 5;  // ty = 0..7
  #pragma unroll
  for (int i = 0; i < 4; ++i)
    tile[ty + 8 * i][tx] = in[(size_t)(kb + ty + 8 * i) * ldin + nb + tx];
  __syncthreads();
  #pragma unroll
  for (int i = 0; i < 4; ++i)
    out[(size_t)(nb + ty + 8 * i) * K + kb + tx] = f2bf(tile[tx][ty + 8 * i]);
}

// bf16 (R,Cc) row-major -> bf16 (Cc,R), batched over blockIdx.z (stride R*Cc).
// 64x64 tiles, short8 (16B) global loads/stores both sides.
__global__ __launch_bounds__(256) void transpose_bf16_kernel(
    const bf16* __restrict__ in, bf16* __restrict__ out, int R, int Cc)
{
  __shared__ unsigned short tile[64][80];   // 160B row stride (16B aligned)
  const size_t ib = (size_t)blockIdx.z * R * Cc;
  const int rb = blockIdx.y * 64, cb = blockIdx.x * 64;
  const int tr = threadIdx.x >> 3, ch = threadIdx.x & 7;
  #pragma unroll
  for (int p = 0; p < 2; ++p) {
    const int r = tr + 32 * p;
    const short8 v = *(const short8*)(in + ib + (size_t)(rb + r) * Cc + cb + ch * 8);
    *(short8*)&tile[r][ch * 8] = v;
  }
  __syncthreads();
  #pragma unroll
  for (int p = 0; p < 2; ++p) {
    const int c = tr + 32 * p;              // output row (col of input)
    short8 v;
    #pragma unroll
    for (int e = 0; e < 8; ++e) v[e] = (short)tile[ch * 8 + e][c];
    *(short8*)(out + ib + (size_t)(cb + c) * R + rb + ch * 8) = v;
  }
}

// ---------------------------------------------------------------------------
// MFMA bf16 GEMM (m97 structure): C = A @ Bt^T (+bias +pos, opt gelu).
// A: (M,K) bf16 row-major. Bt: (N,K) bf16 row-major.
template<int BN, int OUTF32, int ACT, int POS>
__global__ __launch_bounds__(256) void mfma_gemm_kernel(
    const bf16* __restrict__ A, const bf16* __restrict__ Bt,
    const float* __restrict__ bias, const float* __restrict__ pos, int posmask,
    void* __restrict__ Cv, int M, int N, int K)
{
  constexpr int WGN = BN / 64;            // wave-grid cols (2 or 1)
  constexpr int WGR = 4 / WGN;            // wave-grid rows (2 or 4)
  constexpr int FM  = 128 / (16 * WGR);   // A fragments per wave (4 or 2)
  __shared__ bf16 As[128 * 32];           // [m][k], row = 64B
  __shared__ bf16 Bs[BN * 32];            // [n][k]
  const int t  = threadIdx.x;
  const int l  = t & 63;
  const int w  = t >> 6;
  const int wr = w / WGN, wc = w % WGN;
  const int lr = l & 15, kg = l >> 4;
  const int m0 = blockIdx.y * 128, n0 = blockIdx.x * BN;

  const bf16* ga = A  + (size_t)(m0 + (t >> 2)) * K + (t & 3) * 8;
  const bf16* gb = Bt + (size_t)(n0 + (t >> 2)) * K + (t & 3) * 8;
  char* asl = (char*)As + t * 16;
  char* bsl = (char*)Bs + t * 16;

  f32x4 acc[FM][4] = {};

  for (int k0 = 0; k0 < K; k0 += 32) {
    gload16(ga, asl);
    gload16(ga + (size_t)64 * K, asl + 4096);
    gload16(gb, bsl);
    if (BN == 128) gload16(gb + (size_t)64 * K, bsl + 4096);
    ga += 32; gb += 32;
    __syncthreads();
    short8 af[FM], bfv[4];
    #pragma unroll
    for (int i = 0; i < FM; ++i)
      af[i] = *(const short8*)&As[(wr * (FM * 16) + i * 16 + lr) * 32 + kg * 8];
    #pragma unroll
    for (int j = 0; j < 4; ++j)
      bfv[j] = *(const short8*)&Bs[(wc * 64 + j * 16 + lr) * 32 + kg * 8];
    #pragma unroll
    for (int i = 0; i < FM; ++i)
      #pragma unroll
      for (int j = 0; j < 4; ++j)
        acc[i][j] = __builtin_amdgcn_mfma_f32_16x16x32_bf16(
            af[i], bfv[j], acc[i][j], 0, 0, 0);
    __syncthreads();
  }

  #pragma unroll
  for (int i = 0; i < FM; ++i) {
    #pragma unroll
    for (int j = 0; j < 4; ++j) {
      const int n = n0 + wc * 64 + j * 16 + lr;
      const float bv = bias[n];
      #pragma unroll
      for (int r = 0; r < 4; ++r) {
        const int m = m0 + wr * (FM * 16) + i * 16 + kg * 4 + r;
        float v = acc[i][j][r] + bv;
        if (POS) v += pos[(size_t)(m & posmask) * N + n];
        if (ACT) v = gelu_exact(v);
        if (OUTF32) ((float*)Cv)[(size_t)m * N + n] = v;
        else        ((bf16*)Cv)[(size_t)m * N + n] = f2bf(v);
      }
    }
  }
}

// ---------------------------------------------------------------------------
// Batched MFMA GEMM for the kp/vp projections: C[z] = A[z] @ Bt[z]^T + bias.
// 64x64 tile, BK=32, 4 waves (2x2), per-wave 32x32. aBatch/bBatch = 0 for
// batch-shared operands. BIASM: bias indexed by m (row) instead of n.
// Output bf16 (M,N) row-major per batch.
template<int BIASM>
__global__ __launch_bounds__(256) void proj_kernel(
    const bf16* __restrict__ A, const bf16* __restrict__ Bt,
    const float* __restrict__ bias, bf16* __restrict__ Cb,
    int M, int N, int K, long aBatch, long bBatch, long cBatch)
{
  __shared__ bf16 As[64 * 32];
  __shared__ bf16 Bs[64 * 32];
  const int t = threadIdx.x, l = t & 63, w = t >> 6;
  const int wr = w >> 1, wc = w & 1;
  const int lr = l & 15, kg = l >> 4;
  const int z = blockIdx.z;
  const int m0 = blockIdx.y * 64, n0 = blockIdx.x * 64;
  const bf16* ga = A  + (size_t)z * aBatch + (size_t)(m0 + (t >> 2)) * K + (t & 3) * 8;
  const bf16* gb = Bt + (size_t)z * bBatch + (size_t)(n0 + (t >> 2)) * K + (t & 3) * 8;
  char* asl = (char*)As + t * 16;
  char* bsl = (char*)Bs + t * 16;
  f32x4 acc[2][2] = {};
  for (int k0 = 0; k0 < K; k0 += 32) {
    gload16(ga, asl);
    gload16(gb, bsl);
    ga += 32; gb += 32;
    __syncthreads();
    short8 af[2], bfr[2];
    #pragma unroll
    for (int i = 0; i < 2; ++i)
      af[i] = *(const short8*)&As[(wr * 32 + i * 16 + lr) * 32 + kg * 8];
    #pragma unroll
    for (int j = 0; j < 2; ++j)
      bfr[j] = *(const short8*)&Bs[(wc * 32 + j * 16 + lr) * 32 + kg * 8];
    #pragma unroll
    for (int i = 0; i < 2; ++i)
      #pragma unroll
      for (int j = 0; j < 2; ++j)
        acc[i][j] = __builtin_amdgcn_mfma_f32_16x16x32_bf16(
            af[i], bfr[j], acc[i][j], 0, 0, 0);
    __syncthreads();
  }
  #pragma unroll
  for (int i = 0; i < 2; ++i)
    #pragma unroll
    for (int j = 0; j < 2; ++j) {
      const int n = n0 + wc * 32 + j * 16 + lr;
      #pragma unroll
      for (int r = 0; r < 4; ++r) {
        const int m = m0 + wr * 32 + i * 16 + kg * 4 + r;
        const float v = acc[i][j][r] + (BIASM ? bias[m] : bias[n]);
        Cb[(size_t)z * cBatch + (size_t)m * N + n] = f2bf(v);
      }
    }
}

// ---------------------------------------------------------------------------
// MFMA attention. One block = (b,h) x 64 q-rows, 4 waves (wave w owns q rows
// w*16..w*16+15). LDS (XOR-swizzled, byte ^= (row&7)<<4 on all tiles):
//   qs  [64][64]  bf16 (8KB)   q tile
//   us  [256][64] bf16 (32KB)  kpT, overwritten by P [64][256] after S-phase
//   vs  [64][256] bf16 (32KB)  vp tile
// S = q @ kpT^T (MFMA), softmax in C-frag registers (in-lane over 16 p-tiles
// + shfl_xor over 16-lane group), P -> LDS bf16, O^T = vp @ P^T (MFMA, d-major
// output -> packed ushort4 stores in natural [b,h,q,d] layout).
__global__ __launch_bounds__(256) void attn_mfma_kernel(
    const bf16* __restrict__ qb, const bf16* __restrict__ kpT,
    const bf16* __restrict__ vp, const float* __restrict__ temp,
    bf16* __restrict__ xat)
{
  __shared__ bf16 qs[64 * 64];
  __shared__ bf16 us[256 * 64];
  __shared__ bf16 vs[64 * 256];
  const int t = threadIdx.x, w = t >> 6, l = t & 63;
  const int lr = l & 15, kg = l >> 4;
  const int b = blockIdx.z, h = blockIdx.y;
  const int q0 = blockIdx.x * 64;
  const int bh = b * H_ + h;
  const float tv = temp[h];

  // ---- stage q / kpT / vp (reg-staged, swizzled 16B writes) ----
  {
    const int rowb = t >> 3, ch = t & 7;        // 128B rows
    #pragma unroll
    for (int p = 0; p < 2; ++p) {
      const int r = rowb + 32 * p;
      const short8 v = *(const short8*)(qb + ((size_t)(b * N1_ + q0 + r)) * C_ + h * HD_ + ch * 8);
      *(short8*)((char*)qs + ((r * 128 + ch * 16) ^ ((r & 7) << 4))) = v;
    }
    const bf16* kpb = kpT + (size_t)bh * (P_ * HD_);
    #pragma unroll
    for (int p = 0; p < 8; ++p) {
      const int r = rowb + 32 * p;
      const short8 v = *(const short8*)(kpb + r * HD_ + ch * 8);
      *(short8*)((char*)us + ((r * 128 + ch * 16) ^ ((r & 7) << 4))) = v;
    }
    const bf16* vpb = vp + (size_t)bh * (HD_ * P_);
    const int rowv = t >> 5, chv = t & 31;      // 512B rows
    #pragma unroll
    for (int p = 0; p < 8; ++p) {
      const int r = rowv + 8 * p;
      const short8 v = *(const short8*)(vpb + r * P_ + chv * 8);
      *(short8*)((char*)vs + ((r * 512 + chv * 16) ^ ((r & 7) << 4))) = v;
    }
  }
  __syncthreads();

  // ---- S-phase: s[j] = q(16 rows) x kpT-tile j (16 p), K=64 ----
  short8 aq[2];
  {
    const int row = w * 16 + lr;
    const int sw = (row & 7) << 4;
    aq[0] = *(const short8*)((const char*)qs + ((row * 128 +  0 + kg * 16) ^ sw));
    aq[1] = *(const short8*)((const char*)qs + ((row * 128 + 64 + kg * 16) ^ sw));
  }
  f32x4 s[16] = {};
  #pragma unroll
  for (int j = 0; j < 16; ++j) {
    const int row = j * 16 + lr;
    const int sw = (row & 7) << 4;
    const short8 b0 = *(const short8*)((const char*)us + ((row * 128 +  0 + kg * 16) ^ sw));
    const short8 b1 = *(const short8*)((const char*)us + ((row * 128 + 64 + kg * 16) ^ sw));
    s[j] = __builtin_amdgcn_mfma_f32_16x16x32_bf16(aq[0], b0, s[j], 0, 0, 0);
    s[j] = __builtin_amdgcn_mfma_f32_16x16x32_bf16(aq[1], b1, s[j], 0, 0, 0);
  }

  // ---- softmax over p (256) per q-row; row q = w*16 + kg*4 + r ----
  float inv_[4];
  #pragma unroll
  for (int j = 0; j < 16; ++j)
    #pragma unroll
    for (int r = 0; r < 4; ++r) s[j][r] *= tv;
  #pragma unroll
  for (int r = 0; r < 4; ++r) {
    float m = s[0][r];
    #pragma unroll
    for (int j = 1; j < 16; ++j) m = fmaxf(m, s[j][r]);
    #pragma unroll
    for (int off = 1; off < 16; off <<= 1) m = fmaxf(m, __shfl_xor(m, off));
    float sum = 0.f;
    #pragma unroll
    for (int j = 0; j < 16; ++j) { s[j][r] = __expf(s[j][r] - m); sum += s[j][r]; }
    #pragma unroll
    for (int off = 1; off < 16; off <<= 1) sum += __shfl_xor(sum, off);
    inv_[r] = 1.0f / sum;
  }
  __syncthreads();   // all waves done reading kpT from us

  // ---- write P (bf16) into us as [q 64][p 256], swizzled ----
  #pragma unroll
  for (int r = 0; r < 4; ++r) {
    const int q = w * 16 + kg * 4 + r;
    const int sw = (q & 7) << 4;
    #pragma unroll
    for (int j = 0; j < 16; ++j) {
      const int p = j * 16 + lr;
      ((unsigned short*)us)[((q * 512 + p * 2) ^ sw) >> 1] = f2bfu(s[j][r] * inv_[r]);
    }
  }
  __syncthreads();

  // ---- PV-phase: O^T = vp @ P^T  (A = vp d-rows, B = P q-rows) ----
  f32x4 o[4] = {};
  #pragma unroll
  for (int kc = 0; kc < 8; ++kc) {
    const int qrow = w * 16 + lr;
    const short8 pb = *(const short8*)((const char*)us +
        ((qrow * 512 + kc * 64 + kg * 16) ^ ((qrow & 7) << 4)));
    #pragma unroll
    for (int i = 0; i < 4; ++i) {
      const int drow = i * 16 + lr;
      const short8 vb = *(const short8*)((const char*)vs +
          ((drow * 512 + kc * 64 + kg * 16) ^ ((drow & 7) << 4)));
      o[i] = __builtin_amdgcn_mfma_f32_16x16x32_bf16(vb, pb, o[i], 0, 0, 0);
    }
  }
  // D[m=d][n=q]: q = w*16 + lr, d = i*16 + kg*4 + r (4 consecutive -> ushort4)
  const size_t obase = ((size_t)bh * N1_ + q0 + w * 16 + lr) * HD_;
  #pragma unroll
  for (int i = 0; i < 4; ++i) {
    ushort4 pk;
    pk.x = f2bfu(o[i][0]); pk.y = f2bfu(o[i][1]);
    pk.z = f2bfu(o[i][2]); pk.w = f2bfu(o[i][3]);
    *(ushort4*)((bf16*)xat + obase + i * 16 + kg * 4) = pk;
  }
}

// ---------------------------------------------------------------------------
__global__ __launch_bounds__(256) void norm1_kernel(
    const bf16* __restrict__ xat, const bf16* __restrict__ qb,
    bf16* __restrict__ xb)
{
  const int row = blockIdx.x;
  const int b = row >> 12, np = row & 4095;
  const int d = np >> 6, h = (np >> 3) & 7, qhi = np & 7;
  const int c0 = threadIdx.x, c1 = threadIdx.x + 256;
  const size_t sbase = (size_t)((b * H_ + h) * N1_ + qhi * 512);
  float v0 = bf2f(xat[(sbase + c0) * HD_ + d]) + bf2f(qb[(size_t)row * C_ + c0]);
  float v1 = bf2f(xat[(sbase + c1) * HD_ + d]) + bf2f(qb[(size_t)row * C_ + c1]);
  float ss = v0 * v0 + v1 * v1;
  #pragma unroll
  for (int off = 32; off > 0; off >>= 1) ss += __shfl_xor(ss, off);
  __shared__ float sw[4];
  if ((threadIdx.x & 63) == 0) sw[threadIdx.x >> 6] = ss;
  __syncthreads();
  const float tot = sw[0] + sw[1] + sw[2] + sw[3];
  const float scale = 1.0f / fmaxf(sqrtf(tot), 1e-12f);
  xb[(size_t)row * C_ + c0] = f2bf(v0 * scale);
  xb[(size_t)row * C_ + c1] = f2bf(v1 * scale);
}

__global__ __launch_bounds__(256) void norm2_kernel(
    const float* __restrict__ yb, const bf16* __restrict__ xb,
    float* __restrict__ outp)
{
  const int row = blockIdx.x;
  const int c0 = threadIdx.x, c1 = threadIdx.x + 256;
  float v0 = yb[(size_t)row * C_ + c0] + bf2f(xb[(size_t)row * C_ + c0]);
  float v1 = yb[(size_t)row * C_ + c1] + bf2f(xb[(size_t)row * C_ + c1]);
  float ss = v0 * v0 + v1 * v1;
  #pragma unroll
  for (int off = 32; off > 0; off >>= 1) ss += __shfl_xor(ss, off);
  __shared__ float sw[4];
  if ((threadIdx.x & 63) == 0) sw[threadIdx.x >> 6] = ss;
  __syncthreads();
  const float tot = sw[0] + sw[1] + sw[2] + sw[3];
  const float scale = 1.0f / fmaxf(sqrtf(tot), 1e-12f);
  outp[(size_t)row * C_ + c0] = v0 * scale;
  outp[(size_t)row * C_ + c1] = v1 * scale;
}

// ---------------------------------------------------------------------------
extern "C" void kernel_launch(void* const* d_in, const int* in_sizes, int n_in,
                              void* d_out, int out_size, void* d_ws, size_t ws_size,
                              hipStream_t stream)
{
  const float* x1   = (const float*)d_in[0];
  const float* x2   = (const float*)d_in[1];
  const float* Wq   = (const float*)d_in[2];
  const float* bq   = (const float*)d_in[3];
  const float* Wkv  = (const float*)d_in[4];
  const float* bkv  = (const float*)d_in[5];
  const float* Wp   = (const float*)d_in[6];
  const float* bp   = (const float*)d_in[7];
  const float* posq = (const float*)d_in[8];
  const float* posk = (const float*)d_in[9];
  const float* temp = (const float*)d_in[10];
  const float* W1   = (const float*)d_in[11];
  const float* b1   = (const float*)d_in[12];
  const float* W2   = (const float*)d_in[13];
  const float* b2   = (const float*)d_in[14];

  // Workspace layout (peak < 118 MiB):
  //  A [0,32M):      x2b -> x1b -> xb
  //  B [32,64M):     k -> v -> xat -> hb
  //  C [64,96M):     kT -> vT -> qb
  //  [96,98M):       kpT  -> W1t (after attn)
  //  [98,100M):      vp   -> W2t (after attn)
  //  [100,102M):     WpT
  //  [102,118M):     Wqt/Wkt/Wvt (pre-MLP) -> yb (MLP phase)
  char* ws = (char*)d_ws;
  bf16*  Abuf = (bf16*)(ws);
  bf16*  Bbuf = (bf16*)(ws + 33554432);
  bf16*  Cbuf = (bf16*)(ws + 67108864);
  bf16*  kpT  = (bf16*)(ws + 100663296);
  bf16*  vpb  = (bf16*)(ws + 102760448);
  bf16*  WpT  = (bf16*)(ws + 104857600);
  bf16*  W1t  = (bf16*)(ws + 100663296);   // aliases kpT (dead after attn)
  bf16*  W2t  = (bf16*)(ws + 102760448);   // aliases vp
  bf16*  Wqt  = (bf16*)(ws + 106954752);
  bf16*  Wkt  = (bf16*)(ws + 107479040);
  bf16*  Wvt  = (bf16*)(ws + 108003328);
  float* yb   = (float*)(ws + 106954752);  // aliases Wq/Wk/Wv_t (dead in MLP)
  float* outp = (float*)d_out;

  const dim3 blk(256);
  const int Mrows = B_ * N1_;       // 32768
  const int CH = 8192;              // MLP row-chunk
  bf16* xat = Bbuf;
  bf16* xb  = Abuf;
  bf16* hb  = Bbuf;
  bf16* qb  = Cbuf;

  // x2 -> bf16
  f2b_kernel<<<dim3(2048), blk, 0, stream>>>(x2, Abuf, (B_ * N2_ * C_) / 4);
  // weight transposes: f32 (K,N) -> bf16 (N,K)
  transpose_f2b_kernel<<<dim3(16, 16), blk, 0, stream>>>(Wkv,      Wkt, C_, C_, 2 * C_);
  transpose_f2b_kernel<<<dim3(16, 16), blk, 0, stream>>>(Wkv + C_, Wvt, C_, C_, 2 * C_);
  transpose_f2b_kernel<<<dim3(16, 16), blk, 0, stream>>>(Wq,       Wqt, C_, C_, C_);
  transpose_f2b_kernel<<<dim3(8, 128), blk, 0, stream>>>(Wp,       WpT, N2_, P_, P_);

  // k = x2@Wkv[:, :C] + bkv[:C] + pos_k  -> B
  mfma_gemm_kernel<128,0,0,1><<<dim3(C_/128, Mrows/128), blk, 0, stream>>>(
      Abuf, Wkt, bkv, posk, N2_ - 1, Bbuf, Mrows, C_, C_);
  // kT[b,c,n] -> C
  transpose_bf16_kernel<<<dim3(C_/64, N2_/64, B_), blk, 0, stream>>>(
      Bbuf, Cbuf, N2_, C_);
  // kpT[b,h,p,d] = WpT @ kT[b,h]^T + bp (row-bias)
  proj_kernel<1><<<dim3(1, 4, B_*H_), blk, 0, stream>>>(
      WpT, Cbuf, bp, kpT, P_, HD_, N2_, 0L, (long)HD_*N2_, (long)P_*HD_);
  // v = x2@Wkv[:, C:] + bkv[C:]  -> B (k dead)
  mfma_gemm_kernel<128,0,0,0><<<dim3(C_/128, Mrows/128), blk, 0, stream>>>(
      Abuf, Wvt, bkv + C_, nullptr, 0, Bbuf, Mrows, C_, C_);
  // vT -> C (kT dead)
  transpose_bf16_kernel<<<dim3(C_/64, N2_/64, B_), blk, 0, stream>>>(
      Bbuf, Cbuf, N2_, C_);
  // vp[b,h,d,p] = vT[b,h] @ WpT^T + bp (col-bias)
  proj_kernel<0><<<dim3(4, 1, B_*H_), blk, 0, stream>>>(
      Cbuf, WpT, bp, vpb, HD_, P_, N2_, (long)HD_*N2_, 0L, (long)HD_*P_);
  // x1 -> bf16 (x2b dead)
  f2b_kernel<<<dim3(2048), blk, 0, stream>>>(x1, Abuf, (B_ * N1_ * C_) / 4);
  // q = x1@Wq + bq + pos_q  -> C (vT dead)
  mfma_gemm_kernel<128,0,0,1><<<dim3(C_/128, Mrows/128), blk, 0, stream>>>(
      Abuf, Wqt, bq, posq, N1_ - 1, qb, Mrows, C_, C_);
  // MFMA attention -> xat (region B; v dead)
  attn_mfma_kernel<<<dim3(N1_/64, H_, B_), blk, 0, stream>>>(
      qb, kpT, vpb, temp, xat);
  // MLP weight transposes (kpT/vp dead)
  transpose_f2b_kernel<<<dim3(64, 16), blk, 0, stream>>>(W1, W1t, C_,   MLP_, MLP_);
  transpose_f2b_kernel<<<dim3(16, 64), blk, 0, stream>>>(W2, W2t, MLP_, C_,   C_);
  // x = l2norm(scramble(attn) + q) -> region A (x1b dead)
  norm1_kernel<<<dim3(Mrows), blk, 0, stream>>>(xat, qb, xb);
  // MLP + final norm, chunked
  for (int c = 0; c < Mrows / CH; ++c) {
    const bf16* xc = xb + (size_t)c * CH * C_;
    mfma_gemm_kernel<128,0,1,0><<<dim3(MLP_/128, CH/128), blk, 0, stream>>>(
        xc, W1t, b1, nullptr, 0, hb, CH, MLP_, C_);
    mfma_gemm_kernel<64,1,0,0><<<dim3(C_/64, CH/128), blk, 0, stream>>>(
        hb, W2t, b2, nullptr, 0, yb, CH, C_, MLP_);
    norm2_kernel<<<dim3(CH), blk, 0, stream>>>(
        yb, xc, outp + (size_t)c * CH * C_);
  }
}

// Round 3
// 835.645 us; speedup vs baseline: 6.1050x; 1.1175x over previous
//
#include <hip/hip_runtime.h>
#include <hip/hip_bf16.h>
#include <math.h>

// Problem constants
#define B_    8
#define N1_   4096
#define N2_   4096
#define C_    512
#define P_    256
#define H_    8
#define MLP_  2048
#define HD_   64

typedef __hip_bfloat16 bf16;
typedef __attribute__((ext_vector_type(8))) short short8;   // 8 bf16 (4 VGPRs)
typedef __attribute__((ext_vector_type(4))) float f32x4;

__device__ __forceinline__ float bf2f(bf16 v) { return __bfloat162float(v); }
__device__ __forceinline__ bf16  f2bf(float v) { return __float2bfloat16(v); }
__device__ __forceinline__ float ubf2f(unsigned short u) {
  union { float f; unsigned int i; } cv; cv.i = ((unsigned int)u) << 16; return cv.f;
}
__device__ __forceinline__ unsigned short f2bfu(float v) {
  union { bf16 b; unsigned short u; } cv; cv.b = __float2bfloat16(v); return cv.u;
}
__device__ __forceinline__ float gelu_exact(float x) {
  return 0.5f * x * (1.0f + erff(x * 0.70710678118654752f));
}

// async global->LDS, 16B per lane (global_load_lds_dwordx4)
__device__ __forceinline__ void gload16(const void* g, void* l) {
  __builtin_amdgcn_global_load_lds(
      (const __attribute__((address_space(1))) void*)g,
      (__attribute__((address_space(3))) void*)l, 16, 0, 0);
}

// ---------------------------------------------------------------------------
// f32 -> bf16 elementwise (x1/x2 conversion). n4 = count/4.
__global__ __launch_bounds__(256) void f2b_kernel(
    const float* __restrict__ in, bf16* __restrict__ out, int n4)
{
  int i = blockIdx.x * 256 + threadIdx.x;
  const int stride = gridDim.x * 256;
  for (; i < n4; i += stride) {
    const float4 v = ((const float4*)in)[i];
    ushort4 o;
    o.x = f2bfu(v.x); o.y = f2bfu(v.y); o.z = f2bfu(v.z); o.w = f2bfu(v.w);
    ((ushort4*)out)[i] = o;
  }
}

// f32 (K,N) row-major (leading dim ldin) -> bf16 (N,K) transposed.
__global__ __launch_bounds__(256) void transpose_f2b_kernel(
    const float* __restrict__ in, bf16* __restrict__ out, int K, int N, int ldin)
{
  __shared__ float tile[32][33];
  const int kb = blockIdx.y * 32, nb = blockIdx.x * 32;
  const int tx = threadIdx.x & 31, ty = threadIdx.x >> 5;  // ty = 0..7
  #pragma unroll
  for (int i = 0; i < 4; ++i)
    tile[ty + 8 * i][tx] = in[(size_t)(kb + ty + 8 * i) * ldin + nb + tx];
  __syncthreads();
  #pragma unroll
  for (int i = 0; i < 4; ++i)
    out[(size_t)(nb + ty + 8 * i) * K + kb + tx] = f2bf(tile[tx][ty + 8 * i]);
}

// bf16 (R,Cc) row-major -> bf16 (Cc,R), batched over blockIdx.z (stride R*Cc).
// 64x64 tiles, short8 (16B) global loads/stores both sides.
__global__ __launch_bounds__(256) void transpose_bf16_kernel(
    const bf16* __restrict__ in, bf16* __restrict__ out, int R, int Cc)
{
  __shared__ unsigned short tile[64][80];   // 160B row stride (16B aligned)
  const size_t ib = (size_t)blockIdx.z * R * Cc;
  const int rb = blockIdx.y * 64, cb = blockIdx.x * 64;
  const int tr = threadIdx.x >> 3, ch = threadIdx.x & 7;
  #pragma unroll
  for (int p = 0; p < 2; ++p) {
    const int r = tr + 32 * p;
    const short8 v = *(const short8*)(in + ib + (size_t)(rb + r) * Cc + cb + ch * 8);
    *(short8*)&tile[r][ch * 8] = v;
  }
  __syncthreads();
  #pragma unroll
  for (int p = 0; p < 2; ++p) {
    const int c = tr + 32 * p;              // output row (col of input)
    short8 v;
    #pragma unroll
    for (int e = 0; e < 8; ++e) v[e] = (short)tile[ch * 8 + e][c];
    *(short8*)(out + ib + (size_t)(cb + c) * R + rb + ch * 8) = v;
  }
}

// ---------------------------------------------------------------------------
// MFMA bf16 GEMM (m97 structure): C = A @ Bt^T (+bias +pos, opt gelu).
// A: (M,K) bf16 row-major. Bt: (N,K) bf16 row-major.
template<int BN, int OUTF32, int ACT, int POS>
__global__ __launch_bounds__(256) void mfma_gemm_kernel(
    const bf16* __restrict__ A, const bf16* __restrict__ Bt,
    const float* __restrict__ bias, const float* __restrict__ pos, int posmask,
    void* __restrict__ Cv, int M, int N, int K)
{
  constexpr int WGN = BN / 64;            // wave-grid cols (2 or 1)
  constexpr int WGR = 4 / WGN;            // wave-grid rows (2 or 4)
  constexpr int FM  = 128 / (16 * WGR);   // A fragments per wave (4 or 2)
  __shared__ bf16 As[128 * 32];           // [m][k], row = 64B
  __shared__ bf16 Bs[BN * 32];            // [n][k]
  const int t  = threadIdx.x;
  const int l  = t & 63;
  const int w  = t >> 6;
  const int wr = w / WGN, wc = w % WGN;
  const int lr = l & 15, kg = l >> 4;
  const int m0 = blockIdx.y * 128, n0 = blockIdx.x * BN;

  const bf16* ga = A  + (size_t)(m0 + (t >> 2)) * K + (t & 3) * 8;
  const bf16* gb = Bt + (size_t)(n0 + (t >> 2)) * K + (t & 3) * 8;
  char* asl = (char*)As + t * 16;
  char* bsl = (char*)Bs + t * 16;

  f32x4 acc[FM][4] = {};

  for (int k0 = 0; k0 < K; k0 += 32) {
    gload16(ga, asl);
    gload16(ga + (size_t)64 * K, asl + 4096);
    gload16(gb, bsl);
    if (BN == 128) gload16(gb + (size_t)64 * K, bsl + 4096);
    ga += 32; gb += 32;
    __syncthreads();
    short8 af[FM], bfv[4];
    #pragma unroll
    for (int i = 0; i < FM; ++i)
      af[i] = *(const short8*)&As[(wr * (FM * 16) + i * 16 + lr) * 32 + kg * 8];
    #pragma unroll
    for (int j = 0; j < 4; ++j)
      bfv[j] = *(const short8*)&Bs[(wc * 64 + j * 16 + lr) * 32 + kg * 8];
    #pragma unroll
    for (int i = 0; i < FM; ++i)
      #pragma unroll
      for (int j = 0; j < 4; ++j)
        acc[i][j] = __builtin_amdgcn_mfma_f32_16x16x32_bf16(
            af[i], bfv[j], acc[i][j], 0, 0, 0);
    __syncthreads();
  }

  #pragma unroll
  for (int i = 0; i < FM; ++i) {
    #pragma unroll
    for (int j = 0; j < 4; ++j) {
      const int n = n0 + wc * 64 + j * 16 + lr;
      const float bv = bias[n];
      #pragma unroll
      for (int r = 0; r < 4; ++r) {
        const int m = m0 + wr * (FM * 16) + i * 16 + kg * 4 + r;
        float v = acc[i][j][r] + bv;
        if (POS) v += pos[(size_t)(m & posmask) * N + n];
        if (ACT) v = gelu_exact(v);
        if (OUTF32) ((float*)Cv)[(size_t)m * N + n] = v;
        else        ((bf16*)Cv)[(size_t)m * N + n] = f2bf(v);
      }
    }
  }
}

// ---------------------------------------------------------------------------
// Batched MFMA GEMM for the kp/vp projections: C[z] = A[z] @ Bt[z]^T + bias.
template<int BIASM>
__global__ __launch_bounds__(256) void proj_kernel(
    const bf16* __restrict__ A, const bf16* __restrict__ Bt,
    const float* __restrict__ bias, bf16* __restrict__ Cb,
    int M, int N, int K, long aBatch, long bBatch, long cBatch)
{
  __shared__ bf16 As[64 * 32];
  __shared__ bf16 Bs[64 * 32];
  const int t = threadIdx.x, l = t & 63, w = t >> 6;
  const int wr = w >> 1, wc = w & 1;
  const int lr = l & 15, kg = l >> 4;
  const int z = blockIdx.z;
  const int m0 = blockIdx.y * 64, n0 = blockIdx.x * 64;
  const bf16* ga = A  + (size_t)z * aBatch + (size_t)(m0 + (t >> 2)) * K + (t & 3) * 8;
  const bf16* gb = Bt + (size_t)z * bBatch + (size_t)(n0 + (t >> 2)) * K + (t & 3) * 8;
  char* asl = (char*)As + t * 16;
  char* bsl = (char*)Bs + t * 16;
  f32x4 acc[2][2] = {};
  for (int k0 = 0; k0 < K; k0 += 32) {
    gload16(ga, asl);
    gload16(gb, bsl);
    ga += 32; gb += 32;
    __syncthreads();
    short8 af[2], bfr[2];
    #pragma unroll
    for (int i = 0; i < 2; ++i)
      af[i] = *(const short8*)&As[(wr * 32 + i * 16 + lr) * 32 + kg * 8];
    #pragma unroll
    for (int j = 0; j < 2; ++j)
      bfr[j] = *(const short8*)&Bs[(wc * 32 + j * 16 + lr) * 32 + kg * 8];
    #pragma unroll
    for (int i = 0; i < 2; ++i)
      #pragma unroll
      for (int j = 0; j < 2; ++j)
        acc[i][j] = __builtin_amdgcn_mfma_f32_16x16x32_bf16(
            af[i], bfr[j], acc[i][j], 0, 0, 0);
    __syncthreads();
  }
  #pragma unroll
  for (int i = 0; i < 2; ++i)
    #pragma unroll
    for (int j = 0; j < 2; ++j) {
      const int n = n0 + wc * 32 + j * 16 + lr;
      #pragma unroll
      for (int r = 0; r < 4; ++r) {
        const int m = m0 + wr * 32 + i * 16 + kg * 4 + r;
        const float v = acc[i][j][r] + (BIASM ? bias[m] : bias[n]);
        Cb[(size_t)z * cBatch + (size_t)m * N + n] = f2bf(v);
      }
    }
}

// ---------------------------------------------------------------------------
// MFMA attention. One block = (b,h) x 64 q-rows, 4 waves. Output is written
// TRANSPOSED: xatT[b,h,d,q] (so norm1's scramble gather becomes contiguous).
// PV already produces O^T (d-major fragments), so the transposed store is
// scalar-bf16 with lr-contiguous q (32B segments per 16-lane group).
__global__ __launch_bounds__(256) void attn_mfma_kernel(
    const bf16* __restrict__ qb, const bf16* __restrict__ kpT,
    const bf16* __restrict__ vp, const float* __restrict__ temp,
    bf16* __restrict__ xatT)
{
  __shared__ bf16 qs[64 * 64];
  __shared__ bf16 us[256 * 64];
  __shared__ bf16 vs[64 * 256];
  const int t = threadIdx.x, w = t >> 6, l = t & 63;
  const int lr = l & 15, kg = l >> 4;
  const int b = blockIdx.z, h = blockIdx.y;
  const int q0 = blockIdx.x * 64;
  const int bh = b * H_ + h;
  const float tv = temp[h];

  // ---- stage q / kpT / vp (reg-staged, swizzled 16B writes) ----
  {
    const int rowb = t >> 3, ch = t & 7;        // 128B rows
    #pragma unroll
    for (int p = 0; p < 2; ++p) {
      const int r = rowb + 32 * p;
      const short8 v = *(const short8*)(qb + ((size_t)(b * N1_ + q0 + r)) * C_ + h * HD_ + ch * 8);
      *(short8*)((char*)qs + ((r * 128 + ch * 16) ^ ((r & 7) << 4))) = v;
    }
    const bf16* kpb = kpT + (size_t)bh * (P_ * HD_);
    #pragma unroll
    for (int p = 0; p < 8; ++p) {
      const int r = rowb + 32 * p;
      const short8 v = *(const short8*)(kpb + r * HD_ + ch * 8);
      *(short8*)((char*)us + ((r * 128 + ch * 16) ^ ((r & 7) << 4))) = v;
    }
    const bf16* vpb = vp + (size_t)bh * (HD_ * P_);
    const int rowv = t >> 5, chv = t & 31;      // 512B rows
    #pragma unroll
    for (int p = 0; p < 8; ++p) {
      const int r = rowv + 8 * p;
      const short8 v = *(const short8*)(vpb + r * P_ + chv * 8);
      *(short8*)((char*)vs + ((r * 512 + chv * 16) ^ ((r & 7) << 4))) = v;
    }
  }
  __syncthreads();

  // ---- S-phase: s[j] = q(16 rows) x kpT-tile j (16 p), K=64 ----
  short8 aq[2];
  {
    const int row = w * 16 + lr;
    const int sw = (row & 7) << 4;
    aq[0] = *(const short8*)((const char*)qs + ((row * 128 +  0 + kg * 16) ^ sw));
    aq[1] = *(const short8*)((const char*)qs + ((row * 128 + 64 + kg * 16) ^ sw));
  }
  f32x4 s[16] = {};
  #pragma unroll
  for (int j = 0; j < 16; ++j) {
    const int row = j * 16 + lr;
    const int sw = (row & 7) << 4;
    const short8 b0 = *(const short8*)((const char*)us + ((row * 128 +  0 + kg * 16) ^ sw));
    const short8 b1 = *(const short8*)((const char*)us + ((row * 128 + 64 + kg * 16) ^ sw));
    s[j] = __builtin_amdgcn_mfma_f32_16x16x32_bf16(aq[0], b0, s[j], 0, 0, 0);
    s[j] = __builtin_amdgcn_mfma_f32_16x16x32_bf16(aq[1], b1, s[j], 0, 0, 0);
  }

  // ---- softmax over p (256) per q-row; row q = w*16 + kg*4 + r ----
  float inv_[4];
  #pragma unroll
  for (int j = 0; j < 16; ++j)
    #pragma unroll
    for (int r = 0; r < 4; ++r) s[j][r] *= tv;
  #pragma unroll
  for (int r = 0; r < 4; ++r) {
    float m = s[0][r];
    #pragma unroll
    for (int j = 1; j < 16; ++j) m = fmaxf(m, s[j][r]);
    #pragma unroll
    for (int off = 1; off < 16; off <<= 1) m = fmaxf(m, __shfl_xor(m, off));
    float sum = 0.f;
    #pragma unroll
    for (int j = 0; j < 16; ++j) { s[j][r] = __expf(s[j][r] - m); sum += s[j][r]; }
    #pragma unroll
    for (int off = 1; off < 16; off <<= 1) sum += __shfl_xor(sum, off);
    inv_[r] = 1.0f / sum;
  }
  __syncthreads();   // all waves done reading kpT from us

  // ---- write P (bf16) into us as [q 64][p 256], swizzled ----
  #pragma unroll
  for (int r = 0; r < 4; ++r) {
    const int q = w * 16 + kg * 4 + r;
    const int sw = (q & 7) << 4;
    #pragma unroll
    for (int j = 0; j < 16; ++j) {
      const int p = j * 16 + lr;
      ((unsigned short*)us)[((q * 512 + p * 2) ^ sw) >> 1] = f2bfu(s[j][r] * inv_[r]);
    }
  }
  __syncthreads();

  // ---- PV-phase: O^T = vp @ P^T  (A = vp d-rows, B = P q-rows) ----
  f32x4 o[4] = {};
  #pragma unroll
  for (int kc = 0; kc < 8; ++kc) {
    const int qrow = w * 16 + lr;
    const short8 pb = *(const short8*)((const char*)us +
        ((qrow * 512 + kc * 64 + kg * 16) ^ ((qrow & 7) << 4)));
    #pragma unroll
    for (int i = 0; i < 4; ++i) {
      const int drow = i * 16 + lr;
      const short8 vb = *(const short8*)((const char*)vs +
          ((drow * 512 + kc * 64 + kg * 16) ^ ((drow & 7) << 4)));
      o[i] = __builtin_amdgcn_mfma_f32_16x16x32_bf16(vb, pb, o[i], 0, 0, 0);
    }
  }
  // D[m=d][n=q]: q = w*16 + lr, d = i*16 + kg*4 + r.
  // Transposed store: xatT[(bh*64 + d)*4096 + q].
  const int qq = q0 + w * 16 + lr;
  bf16* ob = xatT + (size_t)bh * (HD_ * (size_t)N1_) + qq;
  #pragma unroll
  for (int i = 0; i < 4; ++i)
    #pragma unroll
    for (int r = 0; r < 4; ++r) {
      const int d = i * 16 + kg * 4 + r;
      ob[(size_t)d * N1_] = f2bf(o[i][r]);
    }
}

// ---------------------------------------------------------------------------
// x = l2norm(scramble(attn) + q_skip). With xatT[b,h,d,q] the gather for
// output row n=(d,h,qhi) column c is CONTIGUOUS: xatT[bh][d][qhi*512 + c].
__global__ __launch_bounds__(256) void norm1_kernel(
    const bf16* __restrict__ xatT, const bf16* __restrict__ qb,
    bf16* __restrict__ xb)
{
  const int row = blockIdx.x;                  // b*4096 + n
  const int b = row >> 12, np = row & 4095;
  const int d = np >> 6, h = (np >> 3) & 7, qhi = np & 7;
  const int c = threadIdx.x * 2;
  const size_t tbase = ((size_t)(b * H_ + h) * HD_ + d) * N1_ + qhi * 512 + c;
  const size_t qbase = (size_t)row * C_ + c;
  const ushort2 xa = *(const ushort2*)((const unsigned short*)xatT + tbase);
  const ushort2 qa = *(const ushort2*)((const unsigned short*)qb + qbase);
  float v0 = ubf2f(xa.x) + ubf2f(qa.x);
  float v1 = ubf2f(xa.y) + ubf2f(qa.y);
  float ss = v0 * v0 + v1 * v1;
  #pragma unroll
  for (int off = 32; off > 0; off >>= 1) ss += __shfl_xor(ss, off);
  __shared__ float sw[4];
  if ((threadIdx.x & 63) == 0) sw[threadIdx.x >> 6] = ss;
  __syncthreads();
  const float tot = sw[0] + sw[1] + sw[2] + sw[3];
  const float scale = 1.0f / fmaxf(sqrtf(tot), 1e-12f);
  ushort2 o;
  o.x = f2bfu(v0 * scale);
  o.y = f2bfu(v1 * scale);
  *(ushort2*)((unsigned short*)xb + qbase) = o;
}

__global__ __launch_bounds__(256) void norm2_kernel(
    const float* __restrict__ yb, const bf16* __restrict__ xb,
    float* __restrict__ outp)
{
  const int row = blockIdx.x;
  const int c0 = threadIdx.x, c1 = threadIdx.x + 256;
  float v0 = yb[(size_t)row * C_ + c0] + bf2f(xb[(size_t)row * C_ + c0]);
  float v1 = yb[(size_t)row * C_ + c1] + bf2f(xb[(size_t)row * C_ + c1]);
  float ss = v0 * v0 + v1 * v1;
  #pragma unroll
  for (int off = 32; off > 0; off >>= 1) ss += __shfl_xor(ss, off);
  __shared__ float sw[4];
  if ((threadIdx.x & 63) == 0) sw[threadIdx.x >> 6] = ss;
  __syncthreads();
  const float tot = sw[0] + sw[1] + sw[2] + sw[3];
  const float scale = 1.0f / fmaxf(sqrtf(tot), 1e-12f);
  outp[(size_t)row * C_ + c0] = v0 * scale;
  outp[(size_t)row * C_ + c1] = v1 * scale;
}

// ---------------------------------------------------------------------------
extern "C" void kernel_launch(void* const* d_in, const int* in_sizes, int n_in,
                              void* d_out, int out_size, void* d_ws, size_t ws_size,
                              hipStream_t stream)
{
  const float* x1   = (const float*)d_in[0];
  const float* x2   = (const float*)d_in[1];
  const float* Wq   = (const float*)d_in[2];
  const float* bq   = (const float*)d_in[3];
  const float* Wkv  = (const float*)d_in[4];
  const float* bkv  = (const float*)d_in[5];
  const float* Wp   = (const float*)d_in[6];
  const float* bp   = (const float*)d_in[7];
  const float* posq = (const float*)d_in[8];
  const float* posk = (const float*)d_in[9];
  const float* temp = (const float*)d_in[10];
  const float* W1   = (const float*)d_in[11];
  const float* b1   = (const float*)d_in[12];
  const float* W2   = (const float*)d_in[13];
  const float* b2   = (const float*)d_in[14];

  // Workspace layout (base, pre-MLP):
  //  A [0,32M):      x2b -> x1b -> xb
  //  B [32,64M):     k -> v -> xatT -> hb(start)
  //  C [64,96M):     kT -> vT -> qb
  //  [96,98M):       kpT        (dead after attn)
  //  [98,100M):      vp         (dead after attn)
  //  [100,102M):     WpT        (dead after proj)
  //  [102M..):       Wqt/Wkt/Wvt (dead after q/k/v gemms)
  // MLP phase (xatT/qb dead after norm1): hb from 32M (CH*2048*2 bytes),
  // then W1t/W2t/yb per the CH-dependent offsets below.
  char* ws = (char*)d_ws;
  bf16*  Abuf = (bf16*)(ws);
  bf16*  Bbuf = (bf16*)(ws + 33554432);
  bf16*  Cbuf = (bf16*)(ws + 67108864);
  bf16*  kpT  = (bf16*)(ws + 100663296);
  bf16*  vpb  = (bf16*)(ws + 102760448);
  bf16*  WpT  = (bf16*)(ws + 104857600);
  bf16*  Wqt  = (bf16*)(ws + 106954752);
  bf16*  Wkt  = (bf16*)(ws + 107479040);
  bf16*  Wvt  = (bf16*)(ws + 108003328);
  float* outp = (float*)d_out;

  // MLP chunk size selected by available workspace (largest that fits).
  // need(CH) = 32M (xb) + CH*2048*2 (hb) + 2M (W1t) + 2M (W2t) + CH*512*4 (yb)
  int CH;
  size_t w1t_off, w2t_off, yb_off;
  if (ws_size >= 239075328UL) {            // 228 MiB: single pass
    CH = 32768; w1t_off = 167772160UL; w2t_off = 169869312UL; yb_off = 171966464UL;
  } else if (ws_size >= 138412032UL) {     // 132 MiB: 2 chunks
    CH = 16384; w1t_off = 100663296UL; w2t_off = 102760448UL; yb_off = 104857600UL;
  } else {                                 // known-good 4-chunk layout
    CH = 8192;  w1t_off = 100663296UL; w2t_off = 102760448UL; yb_off = 106954752UL;
  }
  bf16*  W1t = (bf16*)(ws + w1t_off);
  bf16*  W2t = (bf16*)(ws + w2t_off);
  float* yb  = (float*)(ws + yb_off);

  const dim3 blk(256);
  const int Mrows = B_ * N1_;       // 32768
  bf16* xatT = Bbuf;
  bf16* xb   = Abuf;
  bf16* hb   = Bbuf;
  bf16* qb   = Cbuf;

  // x2 -> bf16
  f2b_kernel<<<dim3(2048), blk, 0, stream>>>(x2, Abuf, (B_ * N2_ * C_) / 4);
  // weight transposes: f32 (K,N) -> bf16 (N,K)
  transpose_f2b_kernel<<<dim3(16, 16), blk, 0, stream>>>(Wkv,      Wkt, C_, C_, 2 * C_);
  transpose_f2b_kernel<<<dim3(16, 16), blk, 0, stream>>>(Wkv + C_, Wvt, C_, C_, 2 * C_);
  transpose_f2b_kernel<<<dim3(16, 16), blk, 0, stream>>>(Wq,       Wqt, C_, C_, C_);
  transpose_f2b_kernel<<<dim3(8, 128), blk, 0, stream>>>(Wp,       WpT, N2_, P_, P_);

  // k = x2@Wkv[:, :C] + bkv[:C] + pos_k  -> B
  mfma_gemm_kernel<128,0,0,1><<<dim3(C_/128, Mrows/128), blk, 0, stream>>>(
      Abuf, Wkt, bkv, posk, N2_ - 1, Bbuf, Mrows, C_, C_);
  // kT[b,c,n] -> C
  transpose_bf16_kernel<<<dim3(C_/64, N2_/64, B_), blk, 0, stream>>>(
      Bbuf, Cbuf, N2_, C_);
  // kpT[b,h,p,d] = WpT @ kT[b,h]^T + bp (row-bias)
  proj_kernel<1><<<dim3(1, 4, B_*H_), blk, 0, stream>>>(
      WpT, Cbuf, bp, kpT, P_, HD_, N2_, 0L, (long)HD_*N2_, (long)P_*HD_);
  // v = x2@Wkv[:, C:] + bkv[C:]  -> B (k dead)
  mfma_gemm_kernel<128,0,0,0><<<dim3(C_/128, Mrows/128), blk, 0, stream>>>(
      Abuf, Wvt, bkv + C_, nullptr, 0, Bbuf, Mrows, C_, C_);
  // vT -> C (kT dead)
  transpose_bf16_kernel<<<dim3(C_/64, N2_/64, B_), blk, 0, stream>>>(
      Bbuf, Cbuf, N2_, C_);
  // vp[b,h,d,p] = vT[b,h] @ WpT^T + bp (col-bias)
  proj_kernel<0><<<dim3(4, 1, B_*H_), blk, 0, stream>>>(
      Cbuf, WpT, bp, vpb, HD_, P_, N2_, (long)HD_*N2_, 0L, (long)HD_*P_);
  // x1 -> bf16 (x2b dead)
  f2b_kernel<<<dim3(2048), blk, 0, stream>>>(x1, Abuf, (B_ * N1_ * C_) / 4);
  // q = x1@Wq + bq + pos_q  -> C (vT dead)
  mfma_gemm_kernel<128,0,0,1><<<dim3(C_/128, Mrows/128), blk, 0, stream>>>(
      Abuf, Wqt, bq, posq, N1_ - 1, qb, Mrows, C_, C_);
  // MFMA attention -> xatT[b,h,d,q] (region B; v dead)
  attn_mfma_kernel<<<dim3(N1_/64, H_, B_), blk, 0, stream>>>(
      qb, kpT, vpb, temp, xatT);
  // MLP weight transposes (kpT/vp dead)
  transpose_f2b_kernel<<<dim3(64, 16), blk, 0, stream>>>(W1, W1t, C_,   MLP_, MLP_);
  transpose_f2b_kernel<<<dim3(16, 64), blk, 0, stream>>>(W2, W2t, MLP_, C_,   C_);
  // x = l2norm(scramble(attn) + q) -> region A (x1b dead)
  norm1_kernel<<<dim3(Mrows), blk, 0, stream>>>(xatT, qb, xb);
  // MLP + final norm, chunked (CH rows per chunk)
  for (int c = 0; c < Mrows / CH; ++c) {
    const bf16* xc = xb + (size_t)c * CH * C_;
    mfma_gemm_kernel<128,0,1,0><<<dim3(MLP_/128, CH/128), blk, 0, stream>>>(
        xc, W1t, b1, nullptr, 0, hb, CH, MLP_, C_);
    mfma_gemm_kernel<64,1,0,0><<<dim3(C_/64, CH/128), blk, 0, stream>>>(
        hb, W2t, b2, nullptr, 0, yb, CH, C_, MLP_);
    norm2_kernel<<<dim3(CH), blk, 0, stream>>>(
        yb, xc, outp + (size_t)c * CH * C_);
  }
}

// Round 5
// 783.856 us; speedup vs baseline: 6.5083x; 1.0661x over previous
//
#include <hip/hip_runtime.h>
#include <hip/hip_bf16.h>
#include <math.h>

// Problem constants
#define B_    8
#define N1_   4096
#define N2_   4096
#define C_    512
#define P_    256
#define H_    8
#define MLP_  2048
#define HD_   64

typedef __hip_bfloat16 bf16;
typedef __attribute__((ext_vector_type(8))) short short8;   // 8 bf16 (4 VGPRs)
typedef __attribute__((ext_vector_type(4))) float f32x4;

__device__ __forceinline__ float bf2f(bf16 v) { return __bfloat162float(v); }
__device__ __forceinline__ bf16  f2bf(float v) { return __float2bfloat16(v); }
__device__ __forceinline__ float ubf2f(unsigned short u) {
  union { float f; unsigned int i; } cv; cv.i = ((unsigned int)u) << 16; return cv.f;
}
__device__ __forceinline__ unsigned short f2bfu(float v) {
  union { bf16 b; unsigned short u; } cv; cv.b = __float2bfloat16(v); return cv.u;
}
__device__ __forceinline__ float gelu_exact(float x) {
  return 0.5f * x * (1.0f + erff(x * 0.70710678118654752f));
}

// async global->LDS, 16B per lane (global_load_lds_dwordx4)
__device__ __forceinline__ void gload16(const void* g, void* l) {
  __builtin_amdgcn_global_load_lds(
      (const __attribute__((address_space(1))) void*)g,
      (__attribute__((address_space(3))) void*)l, 16, 0, 0);
}

// ---------------------------------------------------------------------------
// f32 -> bf16 elementwise (x1/x2 conversion). n4 = count/4.
__global__ __launch_bounds__(256) void f2b_kernel(
    const float* __restrict__ in, bf16* __restrict__ out, int n4)
{
  int i = blockIdx.x * 256 + threadIdx.x;
  const int stride = gridDim.x * 256;
  for (; i < n4; i += stride) {
    const float4 v = ((const float4*)in)[i];
    ushort4 o;
    o.x = f2bfu(v.x); o.y = f2bfu(v.y); o.z = f2bfu(v.z); o.w = f2bfu(v.w);
    ((ushort4*)out)[i] = o;
  }
}

// f32 (K,N) row-major (leading dim ldin) -> bf16 (N,K) transposed.
__global__ __launch_bounds__(256) void transpose_f2b_kernel(
    const float* __restrict__ in, bf16* __restrict__ out, int K, int N, int ldin)
{
  __shared__ float tile[32][33];
  const int kb = blockIdx.y * 32, nb = blockIdx.x * 32;
  const int tx = threadIdx.x & 31, ty = threadIdx.x >> 5;  // ty = 0..7
  #pragma unroll
  for (int i = 0; i < 4; ++i)
    tile[ty + 8 * i][tx] = in[(size_t)(kb + ty + 8 * i) * ldin + nb + tx];
  __syncthreads();
  #pragma unroll
  for (int i = 0; i < 4; ++i)
    out[(size_t)(nb + ty + 8 * i) * K + kb + tx] = f2bf(tile[tx][ty + 8 * i]);
}

// bf16 (R,Cc) row-major -> bf16 (Cc,R), batched over blockIdx.z (stride R*Cc).
// 64x64 tiles, short8 (16B) global loads/stores both sides.
__global__ __launch_bounds__(256) void transpose_bf16_kernel(
    const bf16* __restrict__ in, bf16* __restrict__ out, int R, int Cc)
{
  __shared__ unsigned short tile[64][80];   // 160B row stride (16B aligned)
  const size_t ib = (size_t)blockIdx.z * R * Cc;
  const int rb = blockIdx.y * 64, cb = blockIdx.x * 64;
  const int tr = threadIdx.x >> 3, ch = threadIdx.x & 7;
  #pragma unroll
  for (int p = 0; p < 2; ++p) {
    const int r = tr + 32 * p;
    const short8 v = *(const short8*)(in + ib + (size_t)(rb + r) * Cc + cb + ch * 8);
    *(short8*)&tile[r][ch * 8] = v;
  }
  __syncthreads();
  #pragma unroll
  for (int p = 0; p < 2; ++p) {
    const int c = tr + 32 * p;              // output row (col of input)
    short8 v;
    #pragma unroll
    for (int e = 0; e < 8; ++e) v[e] = (short)tile[ch * 8 + e][c];
    *(short8*)(out + ib + (size_t)(cb + c) * R + rb + ch * 8) = v;
  }
}

// ---------------------------------------------------------------------------
// MFMA bf16 GEMM (m97 structure): C = A @ Bt^T (+bias +pos, opt gelu).
// A: (M,K) bf16 row-major. Bt: (N,K) bf16 row-major.
// XCD swizzle: hw flat id h -> tile (h&7)*(nwg/8) + h/8 (requires nwg%8==0;
// identity fallback otherwise). Round-robin h->XCD then gives each XCD a
// contiguous row-major tile range = whole A-panel rows swept N-fastest, so
// each 128-row A panel is fetched from HBM by exactly ONE XCD (L2-resident
// across its N-blocks) and each weight matrix (<=2MB) is L2-resident.
template<int BN, int OUTF32, int ACT, int POS>
__global__ __launch_bounds__(256) void mfma_gemm_kernel(
    const bf16* __restrict__ A, const bf16* __restrict__ Bt,
    const float* __restrict__ bias, const float* __restrict__ pos, int posmask,
    void* __restrict__ Cv, int M, int N, int K)
{
  constexpr int WGN = BN / 64;            // wave-grid cols (2 or 1)
  constexpr int WGR = 4 / WGN;            // wave-grid rows (2 or 4)
  constexpr int FM  = 128 / (16 * WGR);   // A fragments per wave (4 or 2)
  __shared__ bf16 As[128 * 32];           // [m][k], row = 64B
  __shared__ bf16 Bs[BN * 32];            // [n][k]
  const int t  = threadIdx.x;
  const int l  = t & 63;
  const int w  = t >> 6;
  const int wr = w / WGN, wc = w % WGN;
  const int lr = l & 15, kg = l >> 4;

  // ---- XCD-aware tile remap ----
  const int gx  = gridDim.x;
  const int nwg = gx * gridDim.y;
  const int h   = blockIdx.y * gx + blockIdx.x;
  int bx = blockIdx.x, by = blockIdx.y;
  if ((nwg & 7) == 0) {
    const int tid = (h & 7) * (nwg >> 3) + (h >> 3);
    bx = tid % gx; by = tid / gx;
  }
  const int m0 = by * 128, n0 = bx * BN;

  const bf16* ga = A  + (size_t)(m0 + (t >> 2)) * K + (t & 3) * 8;
  const bf16* gb = Bt + (size_t)(n0 + (t >> 2)) * K + (t & 3) * 8;
  char* asl = (char*)As + t * 16;
  char* bsl = (char*)Bs + t * 16;

  f32x4 acc[FM][4] = {};

  for (int k0 = 0; k0 < K; k0 += 32) {
    gload16(ga, asl);
    gload16(ga + (size_t)64 * K, asl + 4096);
    gload16(gb, bsl);
    if (BN == 128) gload16(gb + (size_t)64 * K, bsl + 4096);
    ga += 32; gb += 32;
    __syncthreads();
    short8 af[FM], bfv[4];
    #pragma unroll
    for (int i = 0; i < FM; ++i)
      af[i] = *(const short8*)&As[(wr * (FM * 16) + i * 16 + lr) * 32 + kg * 8];
    #pragma unroll
    for (int j = 0; j < 4; ++j)
      bfv[j] = *(const short8*)&Bs[(wc * 64 + j * 16 + lr) * 32 + kg * 8];
    #pragma unroll
    for (int i = 0; i < FM; ++i)
      #pragma unroll
      for (int j = 0; j < 4; ++j)
        acc[i][j] = __builtin_amdgcn_mfma_f32_16x16x32_bf16(
            af[i], bfv[j], acc[i][j], 0, 0, 0);
    __syncthreads();
  }

  #pragma unroll
  for (int i = 0; i < FM; ++i) {
    #pragma unroll
    for (int j = 0; j < 4; ++j) {
      const int n = n0 + wc * 64 + j * 16 + lr;
      const float bv = bias[n];
      #pragma unroll
      for (int r = 0; r < 4; ++r) {
        const int m = m0 + wr * (FM * 16) + i * 16 + kg * 4 + r;
        float v = acc[i][j][r] + bv;
        if (POS) v += pos[(size_t)(m & posmask) * N + n];
        if (ACT) v = gelu_exact(v);
        if (OUTF32) ((float*)Cv)[(size_t)m * N + n] = v;
        else        ((bf16*)Cv)[(size_t)m * N + n] = f2bf(v);
      }
    }
  }
}

// ---------------------------------------------------------------------------
// Batched MFMA GEMM for the kp/vp projections: C[z] = A[z] @ Bt[z]^T + bias.
template<int BIASM>
__global__ __launch_bounds__(256) void proj_kernel(
    const bf16* __restrict__ A, const bf16* __restrict__ Bt,
    const float* __restrict__ bias, bf16* __restrict__ Cb,
    int M, int N, int K, long aBatch, long bBatch, long cBatch)
{
  __shared__ bf16 As[64 * 32];
  __shared__ bf16 Bs[64 * 32];
  const int t = threadIdx.x, l = t & 63, w = t >> 6;
  const int wr = w >> 1, wc = w & 1;
  const int lr = l & 15, kg = l >> 4;
  const int z = blockIdx.z;
  const int m0 = blockIdx.y * 64, n0 = blockIdx.x * 64;
  const bf16* ga = A  + (size_t)z * aBatch + (size_t)(m0 + (t >> 2)) * K + (t & 3) * 8;
  const bf16* gb = Bt + (size_t)z * bBatch + (size_t)(n0 + (t >> 2)) * K + (t & 3) * 8;
  char* asl = (char*)As + t * 16;
  char* bsl = (char*)Bs + t * 16;
  f32x4 acc[2][2] = {};
  for (int k0 = 0; k0 < K; k0 += 32) {
    gload16(ga, asl);
    gload16(gb, bsl);
    ga += 32; gb += 32;
    __syncthreads();
    short8 af[2], bfr[2];
    #pragma unroll
    for (int i = 0; i < 2; ++i)
      af[i] = *(const short8*)&As[(wr * 32 + i * 16 + lr) * 32 + kg * 8];
    #pragma unroll
    for (int j = 0; j < 2; ++j)
      bfr[j] = *(const short8*)&Bs[(wc * 32 + j * 16 + lr) * 32 + kg * 8];
    #pragma unroll
    for (int i = 0; i < 2; ++i)
      #pragma unroll
      for (int j = 0; j < 2; ++j)
        acc[i][j] = __builtin_amdgcn_mfma_f32_16x16x32_bf16(
            af[i], bfr[j], acc[i][j], 0, 0, 0);
    __syncthreads();
  }
  #pragma unroll
  for (int i = 0; i < 2; ++i)
    #pragma unroll
    for (int j = 0; j < 2; ++j) {
      const int n = n0 + wc * 32 + j * 16 + lr;
      #pragma unroll
      for (int r = 0; r < 4; ++r) {
        const int m = m0 + wr * 32 + i * 16 + kg * 4 + r;
        const float v = acc[i][j][r] + (BIASM ? bias[m] : bias[n]);
        Cb[(size_t)z * cBatch + (size_t)m * N + n] = f2bf(v);
      }
    }
}

// ---------------------------------------------------------------------------
// MFMA attention. One block = (b,h) x 64 q-rows, 4 waves. Output is written
// TRANSPOSED: xatT[b,h,d,q] (so norm1's scramble gather becomes contiguous).
__global__ __launch_bounds__(256) void attn_mfma_kernel(
    const bf16* __restrict__ qb, const bf16* __restrict__ kpT,
    const bf16* __restrict__ vp, const float* __restrict__ temp,
    bf16* __restrict__ xatT)
{
  __shared__ bf16 qs[64 * 64];
  __shared__ bf16 us[256 * 64];
  __shared__ bf16 vs[64 * 256];
  const int t = threadIdx.x, w = t >> 6, l = t & 63;
  const int lr = l & 15, kg = l >> 4;
  const int b = blockIdx.z, h = blockIdx.y;
  const int q0 = blockIdx.x * 64;
  const int bh = b * H_ + h;
  const float tv = temp[h];

  // ---- stage q / kpT / vp (reg-staged, swizzled 16B writes) ----
  {
    const int rowb = t >> 3, ch = t & 7;        // 128B rows
    #pragma unroll
    for (int p = 0; p < 2; ++p) {
      const int r = rowb + 32 * p;
      const short8 v = *(const short8*)(qb + ((size_t)(b * N1_ + q0 + r)) * C_ + h * HD_ + ch * 8);
      *(short8*)((char*)qs + ((r * 128 + ch * 16) ^ ((r & 7) << 4))) = v;
    }
    const bf16* kpb = kpT + (size_t)bh * (P_ * HD_);
    #pragma unroll
    for (int p = 0; p < 8; ++p) {
      const int r = rowb + 32 * p;
      const short8 v = *(const short8*)(kpb + r * HD_ + ch * 8);
      *(short8*)((char*)us + ((r * 128 + ch * 16) ^ ((r & 7) << 4))) = v;
    }
    const bf16* vpb = vp + (size_t)bh * (HD_ * P_);
    const int rowv = t >> 5, chv = t & 31;      // 512B rows
    #pragma unroll
    for (int p = 0; p < 8; ++p) {
      const int r = rowv + 8 * p;
      const short8 v = *(const short8*)(vpb + r * P_ + chv * 8);
      *(short8*)((char*)vs + ((r * 512 + chv * 16) ^ ((r & 7) << 4))) = v;
    }
  }
  __syncthreads();

  // ---- S-phase: s[j] = q(16 rows) x kpT-tile j (16 p), K=64 ----
  short8 aq[2];
  {
    const int row = w * 16 + lr;
    const int sw = (row & 7) << 4;
    aq[0] = *(const short8*)((const char*)qs + ((row * 128 +  0 + kg * 16) ^ sw));
    aq[1] = *(const short8*)((const char*)qs + ((row * 128 + 64 + kg * 16) ^ sw));
  }
  f32x4 s[16] = {};
  #pragma unroll
  for (int j = 0; j < 16; ++j) {
    const int row = j * 16 + lr;
    const int sw = (row & 7) << 4;
    const short8 b0 = *(const short8*)((const char*)us + ((row * 128 +  0 + kg * 16) ^ sw));
    const short8 b1 = *(const short8*)((const char*)us + ((row * 128 + 64 + kg * 16) ^ sw));
    s[j] = __builtin_amdgcn_mfma_f32_16x16x32_bf16(aq[0], b0, s[j], 0, 0, 0);
    s[j] = __builtin_amdgcn_mfma_f32_16x16x32_bf16(aq[1], b1, s[j], 0, 0, 0);
  }

  // ---- softmax over p (256) per q-row; row q = w*16 + kg*4 + r ----
  float inv_[4];
  #pragma unroll
  for (int j = 0; j < 16; ++j)
    #pragma unroll
    for (int r = 0; r < 4; ++r) s[j][r] *= tv;
  #pragma unroll
  for (int r = 0; r < 4; ++r) {
    float m = s[0][r];
    #pragma unroll
    for (int j = 1; j < 16; ++j) m = fmaxf(m, s[j][r]);
    #pragma unroll
    for (int off = 1; off < 16; off <<= 1) m = fmaxf(m, __shfl_xor(m, off));
    float sum = 0.f;
    #pragma unroll
    for (int j = 0; j < 16; ++j) { s[j][r] = __expf(s[j][r] - m); sum += s[j][r]; }
    #pragma unroll
    for (int off = 1; off < 16; off <<= 1) sum += __shfl_xor(sum, off);
    inv_[r] = 1.0f / sum;
  }
  __syncthreads();   // all waves done reading kpT from us

  // ---- write P (bf16) into us as [q 64][p 256], swizzled ----
  #pragma unroll
  for (int r = 0; r < 4; ++r) {
    const int q = w * 16 + kg * 4 + r;
    const int sw = (q & 7) << 4;
    #pragma unroll
    for (int j = 0; j < 16; ++j) {
      const int p = j * 16 + lr;
      ((unsigned short*)us)[((q * 512 + p * 2) ^ sw) >> 1] = f2bfu(s[j][r] * inv_[r]);
    }
  }
  __syncthreads();

  // ---- PV-phase: O^T = vp @ P^T  (A = vp d-rows, B = P q-rows) ----
  f32x4 o[4] = {};
  #pragma unroll
  for (int kc = 0; kc < 8; ++kc) {
    const int qrow = w * 16 + lr;
    const short8 pb = *(const short8*)((const char*)us +
        ((qrow * 512 + kc * 64 + kg * 16) ^ ((qrow & 7) << 4)));
    #pragma unroll
    for (int i = 0; i < 4; ++i) {
      const int drow = i * 16 + lr;
      const short8 vb = *(const short8*)((const char*)vs +
          ((drow * 512 + kc * 64 + kg * 16) ^ ((drow & 7) << 4)));
      o[i] = __builtin_amdgcn_mfma_f32_16x16x32_bf16(vb, pb, o[i], 0, 0, 0);
    }
  }
  // D[m=d][n=q]: q = w*16 + lr, d = i*16 + kg*4 + r.
  // Transposed store: xatT[(bh*64 + d)*4096 + q].
  const int qq = q0 + w * 16 + lr;
  bf16* ob = xatT + (size_t)bh * (HD_ * (size_t)N1_) + qq;
  #pragma unroll
  for (int i = 0; i < 4; ++i)
    #pragma unroll
    for (int r = 0; r < 4; ++r) {
      const int d = i * 16 + kg * 4 + r;
      ob[(size_t)d * N1_] = f2bf(o[i][r]);
    }
}

// ---------------------------------------------------------------------------
// x = l2norm(scramble(attn) + q_skip). With xatT[b,h,d,q] the gather for
// output row n=(d,h,qhi) column c is CONTIGUOUS: xatT[bh][d][qhi*512 + c].
__global__ __launch_bounds__(256) void norm1_kernel(
    const bf16* __restrict__ xatT, const bf16* __restrict__ qb,
    bf16* __restrict__ xb)
{
  const int row = blockIdx.x;                  // b*4096 + n
  const int b = row >> 12, np = row & 4095;
  const int d = np >> 6, h = (np >> 3) & 7, qhi = np & 7;
  const int c = threadIdx.x * 2;
  const size_t tbase = ((size_t)(b * H_ + h) * HD_ + d) * N1_ + qhi * 512 + c;
  const size_t qbase = (size_t)row * C_ + c;
  const ushort2 xa = *(const ushort2*)((const unsigned short*)xatT + tbase);
  const ushort2 qa = *(const ushort2*)((const unsigned short*)qb + qbase);
  float v0 = ubf2f(xa.x) + ubf2f(qa.x);
  float v1 = ubf2f(xa.y) + ubf2f(qa.y);
  float ss = v0 * v0 + v1 * v1;
  #pragma unroll
  for (int off = 32; off > 0; off >>= 1) ss += __shfl_xor(ss, off);
  __shared__ float sw[4];
  if ((threadIdx.x & 63) == 0) sw[threadIdx.x >> 6] = ss;
  __syncthreads();
  const float tot = sw[0] + sw[1] + sw[2] + sw[3];
  const float scale = 1.0f / fmaxf(sqrtf(tot), 1e-12f);
  ushort2 o;
  o.x = f2bfu(v0 * scale);
  o.y = f2bfu(v1 * scale);
  *(ushort2*)((unsigned short*)xb + qbase) = o;
}

__global__ __launch_bounds__(256) void norm2_kernel(
    const float* __restrict__ yb, const bf16* __restrict__ xb,
    float* __restrict__ outp)
{
  const int row = blockIdx.x;
  const int c0 = threadIdx.x, c1 = threadIdx.x + 256;
  float v0 = yb[(size_t)row * C_ + c0] + bf2f(xb[(size_t)row * C_ + c0]);
  float v1 = yb[(size_t)row * C_ + c1] + bf2f(xb[(size_t)row * C_ + c1]);
  float ss = v0 * v0 + v1 * v1;
  #pragma unroll
  for (int off = 32; off > 0; off >>= 1) ss += __shfl_xor(ss, off);
  __shared__ float sw[4];
  if ((threadIdx.x & 63) == 0) sw[threadIdx.x >> 6] = ss;
  __syncthreads();
  const float tot = sw[0] + sw[1] + sw[2] + sw[3];
  const float scale = 1.0f / fmaxf(sqrtf(tot), 1e-12f);
  outp[(size_t)row * C_ + c0] = v0 * scale;
  outp[(size_t)row * C_ + c1] = v1 * scale;
}

// ---------------------------------------------------------------------------
extern "C" void kernel_launch(void* const* d_in, const int* in_sizes, int n_in,
                              void* d_out, int out_size, void* d_ws, size_t ws_size,
                              hipStream_t stream)
{
  const float* x1   = (const float*)d_in[0];
  const float* x2   = (const float*)d_in[1];
  const float* Wq   = (const float*)d_in[2];
  const float* bq   = (const float*)d_in[3];
  const float* Wkv  = (const float*)d_in[4];
  const float* bkv  = (const float*)d_in[5];
  const float* Wp   = (const float*)d_in[6];
  const float* bp   = (const float*)d_in[7];
  const float* posq = (const float*)d_in[8];
  const float* posk = (const float*)d_in[9];
  const float* temp = (const float*)d_in[10];
  const float* W1   = (const float*)d_in[11];
  const float* b1   = (const float*)d_in[12];
  const float* W2   = (const float*)d_in[13];
  const float* b2   = (const float*)d_in[14];

  // Workspace layout (base, pre-MLP):
  //  A [0,32M):      x2b -> x1b -> xb
  //  B [32,64M):     k -> v -> xatT -> hb(start)
  //  C [64,96M):     kT -> vT -> qb
  //  [96,98M):       kpT        (dead after attn)
  //  [98,100M):      vp         (dead after attn)
  //  [100,102M):     WpT        (dead after proj)
  //  [102M..):       Wqt/Wkt/Wvt (dead after q/k/v gemms)
  char* ws = (char*)d_ws;
  bf16*  Abuf = (bf16*)(ws);
  bf16*  Bbuf = (bf16*)(ws + 33554432);
  bf16*  Cbuf = (bf16*)(ws + 67108864);
  bf16*  kpT  = (bf16*)(ws + 100663296);
  bf16*  vpb  = (bf16*)(ws + 102760448);
  bf16*  WpT  = (bf16*)(ws + 104857600);
  bf16*  Wqt  = (bf16*)(ws + 106954752);
  bf16*  Wkt  = (bf16*)(ws + 107479040);
  bf16*  Wvt  = (bf16*)(ws + 108003328);
  float* outp = (float*)d_out;

  // MLP chunk size selected by available workspace (largest that fits).
  int CH;
  size_t w1t_off, w2t_off, yb_off;
  if (ws_size >= 239075328UL) {            // 228 MiB: single pass
    CH = 32768; w1t_off = 167772160UL; w2t_off = 169869312UL; yb_off = 171966464UL;
  } else if (ws_size >= 138412032UL) {     // 132 MiB: 2 chunks
    CH = 16384; w1t_off = 100663296UL; w2t_off = 102760448UL; yb_off = 104857600UL;
  } else {                                 // known-good 4-chunk layout
    CH = 8192;  w1t_off = 100663296UL; w2t_off = 102760448UL; yb_off = 106954752UL;
  }
  bf16*  W1t = (bf16*)(ws + w1t_off);
  bf16*  W2t = (bf16*)(ws + w2t_off);
  float* yb  = (float*)(ws + yb_off);

  const dim3 blk(256);
  const int Mrows = B_ * N1_;       // 32768
  bf16* xatT = Bbuf;
  bf16* xb   = Abuf;
  bf16* hb   = Bbuf;
  bf16* qb   = Cbuf;

  // x2 -> bf16
  f2b_kernel<<<dim3(2048), blk, 0, stream>>>(x2, Abuf, (B_ * N2_ * C_) / 4);
  // weight transposes: f32 (K,N) -> bf16 (N,K)
  transpose_f2b_kernel<<<dim3(16, 16), blk, 0, stream>>>(Wkv,      Wkt, C_, C_, 2 * C_);
  transpose_f2b_kernel<<<dim3(16, 16), blk, 0, stream>>>(Wkv + C_, Wvt, C_, C_, 2 * C_);
  transpose_f2b_kernel<<<dim3(16, 16), blk, 0, stream>>>(Wq,       Wqt, C_, C_, C_);
  transpose_f2b_kernel<<<dim3(8, 128), blk, 0, stream>>>(Wp,       WpT, N2_, P_, P_);

  // k = x2@Wkv[:, :C] + bkv[:C] + pos_k  -> B
  mfma_gemm_kernel<128,0,0,1><<<dim3(C_/128, Mrows/128), blk, 0, stream>>>(
      Abuf, Wkt, bkv, posk, N2_ - 1, Bbuf, Mrows, C_, C_);
  // kT[b,c,n] -> C
  transpose_bf16_kernel<<<dim3(C_/64, N2_/64, B_), blk, 0, stream>>>(
      Bbuf, Cbuf, N2_, C_);
  // kpT[b,h,p,d] = WpT @ kT[b,h]^T + bp (row-bias)
  proj_kernel<1><<<dim3(1, 4, B_*H_), blk, 0, stream>>>(
      WpT, Cbuf, bp, kpT, P_, HD_, N2_, 0L, (long)HD_*N2_, (long)P_*HD_);
  // v = x2@Wkv[:, C:] + bkv[C:]  -> B (k dead)
  mfma_gemm_kernel<128,0,0,0><<<dim3(C_/128, Mrows/128), blk, 0, stream>>>(
      Abuf, Wvt, bkv + C_, nullptr, 0, Bbuf, Mrows, C_, C_);
  // vT -> C (kT dead)
  transpose_bf16_kernel<<<dim3(C_/64, N2_/64, B_), blk, 0, stream>>>(
      Bbuf, Cbuf, N2_, C_);
  // vp[b,h,d,p] = vT[b,h] @ WpT^T + bp (col-bias)
  proj_kernel<0><<<dim3(4, 1, B_*H_), blk, 0, stream>>>(
      Cbuf, WpT, bp, vpb, HD_, P_, N2_, (long)HD_*N2_, 0L, (long)HD_*P_);
  // x1 -> bf16 (x2b dead)
  f2b_kernel<<<dim3(2048), blk, 0, stream>>>(x1, Abuf, (B_ * N1_ * C_) / 4);
  // q = x1@Wq + bq + pos_q  -> C (vT dead)
  mfma_gemm_kernel<128,0,0,1><<<dim3(C_/128, Mrows/128), blk, 0, stream>>>(
      Abuf, Wqt, bq, posq, N1_ - 1, qb, Mrows, C_, C_);
  // MFMA attention -> xatT[b,h,d,q] (region B; v dead)
  attn_mfma_kernel<<<dim3(N1_/64, H_, B_), blk, 0, stream>>>(
      qb, kpT, vpb, temp, xatT);
  // MLP weight transposes (kpT/vp dead)
  transpose_f2b_kernel<<<dim3(64, 16), blk, 0, stream>>>(W1, W1t, C_,   MLP_, MLP_);
  transpose_f2b_kernel<<<dim3(16, 64), blk, 0, stream>>>(W2, W2t, MLP_, C_,   C_);
  // x = l2norm(scramble(attn) + q) -> region A (x1b dead)
  norm1_kernel<<<dim3(Mrows), blk, 0, stream>>>(xatT, qb, xb);
  // MLP + final norm, chunked (CH rows per chunk)
  for (int c = 0; c < Mrows / CH; ++c) {
    const bf16* xc = xb + (size_t)c * CH * C_;
    mfma_gemm_kernel<128,0,1,0><<<dim3(MLP_/128, CH/128), blk, 0, stream>>>(
        xc, W1t, b1, nullptr, 0, hb, CH, MLP_, C_);
    mfma_gemm_kernel<64,1,0,0><<<dim3(C_/64, CH/128), blk, 0, stream>>>(
        hb, W2t, b2, nullptr, 0, yb, CH, C_, MLP_);
    norm2_kernel<<<dim3(CH), blk, 0, stream>>>(
        yb, xc, outp + (size_t)c * CH * C_);
  }
}

// Round 6
// 773.381 us; speedup vs baseline: 6.5965x; 1.0135x over previous
//
#include <hip/hip_runtime.h>
#include <hip/hip_bf16.h>
#include <math.h>

// Problem constants
#define B_    8
#define N1_   4096
#define N2_   4096
#define C_    512
#define P_    256
#define H_    8
#define MLP_  2048
#define HD_   64

typedef __hip_bfloat16 bf16;
typedef __attribute__((ext_vector_type(8))) short short8;   // 8 bf16 (4 VGPRs)
typedef __attribute__((ext_vector_type(4))) float f32x4;

__device__ __forceinline__ float bf2f(bf16 v) { return __bfloat162float(v); }
__device__ __forceinline__ bf16  f2bf(float v) { return __float2bfloat16(v); }
__device__ __forceinline__ float ubf2f(unsigned short u) {
  union { float f; unsigned int i; } cv; cv.i = ((unsigned int)u) << 16; return cv.f;
}
__device__ __forceinline__ unsigned short f2bfu(float v) {
  union { bf16 b; unsigned short u; } cv; cv.b = __float2bfloat16(v); return cv.u;
}
// gelu via A&S 7.1.26 erf (|err| < 1.5e-7 — exact within bf16 rounding).
// ~12 VALU ops vs ocml erff's long branchy path (MLP1 was 57% VALUBusy).
__device__ __forceinline__ float gelu_fast(float x) {
  const float u = fabsf(x) * 0.70710678118654752f;
  const float t = __builtin_amdgcn_rcpf(__builtin_fmaf(0.3275911f, u, 1.0f));
  float p = __builtin_fmaf(1.061405429f, t, -1.453152027f);
  p = __builtin_fmaf(p, t, 1.421413741f);
  p = __builtin_fmaf(p, t, -0.284496736f);
  p = __builtin_fmaf(p, t, 0.254829592f);
  p *= t;
  const float e = __expf(-u * u);
  float erfv = __builtin_fmaf(-p, e, 1.0f);
  erfv = (x < 0.0f) ? -erfv : erfv;
  return 0.5f * x * (1.0f + erfv);
}

// async global->LDS, 16B per lane (global_load_lds_dwordx4)
__device__ __forceinline__ void gload16(const void* g, void* l) {
  __builtin_amdgcn_global_load_lds(
      (const __attribute__((address_space(1))) void*)g,
      (__attribute__((address_space(3))) void*)l, 16, 0, 0);
}

// ---------------------------------------------------------------------------
// f32 -> bf16 elementwise (x1/x2 conversion). n4 = count/4.
__global__ __launch_bounds__(256) void f2b_kernel(
    const float* __restrict__ in, bf16* __restrict__ out, int n4)
{
  int i = blockIdx.x * 256 + threadIdx.x;
  const int stride = gridDim.x * 256;
  for (; i < n4; i += stride) {
    const float4 v = ((const float4*)in)[i];
    ushort4 o;
    o.x = f2bfu(v.x); o.y = f2bfu(v.y); o.z = f2bfu(v.z); o.w = f2bfu(v.w);
    ((ushort4*)out)[i] = o;
  }
}

// f32 (K,N) row-major (leading dim ldin) -> bf16 (N,K) transposed.
__global__ __launch_bounds__(256) void transpose_f2b_kernel(
    const float* __restrict__ in, bf16* __restrict__ out, int K, int N, int ldin)
{
  __shared__ float tile[32][33];
  const int kb = blockIdx.y * 32, nb = blockIdx.x * 32;
  const int tx = threadIdx.x & 31, ty = threadIdx.x >> 5;  // ty = 0..7
  #pragma unroll
  for (int i = 0; i < 4; ++i)
    tile[ty + 8 * i][tx] = in[(size_t)(kb + ty + 8 * i) * ldin + nb + tx];
  __syncthreads();
  #pragma unroll
  for (int i = 0; i < 4; ++i)
    out[(size_t)(nb + ty + 8 * i) * K + kb + tx] = f2bf(tile[tx][ty + 8 * i]);
}

// ---------------------------------------------------------------------------
// MFMA bf16 GEMM (m97 structure): C = A @ Bt^T (+bias +pos, opt gelu).
// A: (M,K) bf16 row-major. Bt: (N,K) bf16 row-major.
// XCD swizzle: hw flat id h -> tile (h&7)*(nwg/8) + h/8 (nwg%8==0 for all our
// grids; identity fallback otherwise) — each XCD owns contiguous row-major
// tiles, so an A panel is fetched by exactly one XCD (L2-resident).
// TRANSC=1: output written TRANSPOSED as [b][N][4096] with m = b*4096+n2
// (per-lane 4 consecutive m -> contiguous ushort4); used for kT/vT so the
// standalone transpose kernels disappear.
template<int BN, int OUTF32, int ACT, int POS, int TRANSC>
__global__ __launch_bounds__(256) void mfma_gemm_kernel(
    const bf16* __restrict__ A, const bf16* __restrict__ Bt,
    const float* __restrict__ bias, const float* __restrict__ pos, int posmask,
    void* __restrict__ Cv, int M, int N, int K)
{
  constexpr int WGN = BN / 64;            // wave-grid cols (2 or 1)
  constexpr int WGR = 4 / WGN;            // wave-grid rows (2 or 4)
  constexpr int FM  = 128 / (16 * WGR);   // A fragments per wave (4 or 2)
  __shared__ bf16 As[128 * 32];           // [m][k], row = 64B
  __shared__ bf16 Bs[BN * 32];            // [n][k]
  const int t  = threadIdx.x;
  const int l  = t & 63;
  const int w  = t >> 6;
  const int wr = w / WGN, wc = w % WGN;
  const int lr = l & 15, kg = l >> 4;

  // ---- XCD-aware tile remap ----
  const int gx  = gridDim.x;
  const int nwg = gx * gridDim.y;
  const int h   = blockIdx.y * gx + blockIdx.x;
  int bx = blockIdx.x, by = blockIdx.y;
  if ((nwg & 7) == 0) {
    const int tid = (h & 7) * (nwg >> 3) + (h >> 3);
    bx = tid % gx; by = tid / gx;
  }
  const int m0 = by * 128, n0 = bx * BN;

  const bf16* ga = A  + (size_t)(m0 + (t >> 2)) * K + (t & 3) * 8;
  const bf16* gb = Bt + (size_t)(n0 + (t >> 2)) * K + (t & 3) * 8;
  char* asl = (char*)As + t * 16;
  char* bsl = (char*)Bs + t * 16;

  f32x4 acc[FM][4] = {};

  for (int k0 = 0; k0 < K; k0 += 32) {
    gload16(ga, asl);
    gload16(ga + (size_t)64 * K, asl + 4096);
    gload16(gb, bsl);
    if (BN == 128) gload16(gb + (size_t)64 * K, bsl + 4096);
    ga += 32; gb += 32;
    __syncthreads();
    short8 af[FM], bfv[4];
    #pragma unroll
    for (int i = 0; i < FM; ++i)
      af[i] = *(const short8*)&As[(wr * (FM * 16) + i * 16 + lr) * 32 + kg * 8];
    #pragma unroll
    for (int j = 0; j < 4; ++j)
      bfv[j] = *(const short8*)&Bs[(wc * 64 + j * 16 + lr) * 32 + kg * 8];
    #pragma unroll
    for (int i = 0; i < FM; ++i)
      #pragma unroll
      for (int j = 0; j < 4; ++j)
        acc[i][j] = __builtin_amdgcn_mfma_f32_16x16x32_bf16(
            af[i], bfv[j], acc[i][j], 0, 0, 0);
    __syncthreads();
  }

  #pragma unroll
  for (int i = 0; i < FM; ++i) {
    #pragma unroll
    for (int j = 0; j < 4; ++j) {
      const int n = n0 + wc * 64 + j * 16 + lr;
      const float bv = bias[n];
      if (TRANSC) {
        const int mb = m0 + wr * (FM * 16) + i * 16 + kg * 4;   // 4-aligned
        ushort4 pk;
        #pragma unroll
        for (int r = 0; r < 4; ++r) {
          const int m = mb + r;
          float v = acc[i][j][r] + bv;
          if (POS) v += pos[(size_t)(m & posmask) * N + n];
          ((unsigned short*)&pk)[r] = f2bfu(v);
        }
        *(ushort4*)&((bf16*)Cv)[((size_t)(mb >> 12) * N + n) * (size_t)N1_ + (mb & 4095)] = pk;
      } else {
        #pragma unroll
        for (int r = 0; r < 4; ++r) {
          const int m = m0 + wr * (FM * 16) + i * 16 + kg * 4 + r;
          float v = acc[i][j][r] + bv;
          if (POS) v += pos[(size_t)(m & posmask) * N + n];
          if (ACT) v = gelu_fast(v);
          if (OUTF32) ((float*)Cv)[(size_t)m * N + n] = v;
          else        ((bf16*)Cv)[(size_t)m * N + n] = f2bf(v);
        }
      }
    }
  }
}

// ---------------------------------------------------------------------------
// Batched MFMA GEMM for the kp/vp projections: C[z] = A[z] @ Bt[z]^T + bias.
template<int BIASM>
__global__ __launch_bounds__(256) void proj_kernel(
    const bf16* __restrict__ A, const bf16* __restrict__ Bt,
    const float* __restrict__ bias, bf16* __restrict__ Cb,
    int M, int N, int K, long aBatch, long bBatch, long cBatch)
{
  __shared__ bf16 As[64 * 32];
  __shared__ bf16 Bs[64 * 32];
  const int t = threadIdx.x, l = t & 63, w = t >> 6;
  const int wr = w >> 1, wc = w & 1;
  const int lr = l & 15, kg = l >> 4;
  const int z = blockIdx.z;
  const int m0 = blockIdx.y * 64, n0 = blockIdx.x * 64;
  const bf16* ga = A  + (size_t)z * aBatch + (size_t)(m0 + (t >> 2)) * K + (t & 3) * 8;
  const bf16* gb = Bt + (size_t)z * bBatch + (size_t)(n0 + (t >> 2)) * K + (t & 3) * 8;
  char* asl = (char*)As + t * 16;
  char* bsl = (char*)Bs + t * 16;
  f32x4 acc[2][2] = {};
  for (int k0 = 0; k0 < K; k0 += 32) {
    gload16(ga, asl);
    gload16(gb, bsl);
    ga += 32; gb += 32;
    __syncthreads();
    short8 af[2], bfr[2];
    #pragma unroll
    for (int i = 0; i < 2; ++i)
      af[i] = *(const short8*)&As[(wr * 32 + i * 16 + lr) * 32 + kg * 8];
    #pragma unroll
    for (int j = 0; j < 2; ++j)
      bfr[j] = *(const short8*)&Bs[(wc * 32 + j * 16 + lr) * 32 + kg * 8];
    #pragma unroll
    for (int i = 0; i < 2; ++i)
      #pragma unroll
      for (int j = 0; j < 2; ++j)
        acc[i][j] = __builtin_amdgcn_mfma_f32_16x16x32_bf16(
            af[i], bfr[j], acc[i][j], 0, 0, 0);
    __syncthreads();
  }
  #pragma unroll
  for (int i = 0; i < 2; ++i)
    #pragma unroll
    for (int j = 0; j < 2; ++j) {
      const int n = n0 + wc * 32 + j * 16 + lr;
      #pragma unroll
      for (int r = 0; r < 4; ++r) {
        const int m = m0 + wr * 32 + i * 16 + kg * 4 + r;
        const float v = acc[i][j][r] + (BIASM ? bias[m] : bias[n]);
        Cb[(size_t)z * cBatch + (size_t)m * N + n] = f2bf(v);
      }
    }
}

// ---------------------------------------------------------------------------
// MFMA attention. One block = (b,h) x 64 q-rows, 4 waves. Output is written
// TRANSPOSED: xatT[b,h,d,q] (so norm1's scramble gather becomes contiguous).
__global__ __launch_bounds__(256) void attn_mfma_kernel(
    const bf16* __restrict__ qb, const bf16* __restrict__ kpT,
    const bf16* __restrict__ vp, const float* __restrict__ temp,
    bf16* __restrict__ xatT)
{
  __shared__ bf16 qs[64 * 64];
  __shared__ bf16 us[256 * 64];
  __shared__ bf16 vs[64 * 256];
  const int t = threadIdx.x, w = t >> 6, l = t & 63;
  const int lr = l & 15, kg = l >> 4;
  const int b = blockIdx.z, h = blockIdx.y;
  const int q0 = blockIdx.x * 64;
  const int bh = b * H_ + h;
  const float tv = temp[h];

  // ---- stage q / kpT / vp (reg-staged, swizzled 16B writes) ----
  {
    const int rowb = t >> 3, ch = t & 7;        // 128B rows
    #pragma unroll
    for (int p = 0; p < 2; ++p) {
      const int r = rowb + 32 * p;
      const short8 v = *(const short8*)(qb + ((size_t)(b * N1_ + q0 + r)) * C_ + h * HD_ + ch * 8);
      *(short8*)((char*)qs + ((r * 128 + ch * 16) ^ ((r & 7) << 4))) = v;
    }
    const bf16* kpb = kpT + (size_t)bh * (P_ * HD_);
    #pragma unroll
    for (int p = 0; p < 8; ++p) {
      const int r = rowb + 32 * p;
      const short8 v = *(const short8*)(kpb + r * HD_ + ch * 8);
      *(short8*)((char*)us + ((r * 128 + ch * 16) ^ ((r & 7) << 4))) = v;
    }
    const bf16* vpb = vp + (size_t)bh * (HD_ * P_);
    const int rowv = t >> 5, chv = t & 31;      // 512B rows
    #pragma unroll
    for (int p = 0; p < 8; ++p) {
      const int r = rowv + 8 * p;
      const short8 v = *(const short8*)(vpb + r * P_ + chv * 8);
      *(short8*)((char*)vs + ((r * 512 + chv * 16) ^ ((r & 7) << 4))) = v;
    }
  }
  __syncthreads();

  // ---- S-phase: s[j] = q(16 rows) x kpT-tile j (16 p), K=64 ----
  short8 aq[2];
  {
    const int row = w * 16 + lr;
    const int sw = (row & 7) << 4;
    aq[0] = *(const short8*)((const char*)qs + ((row * 128 +  0 + kg * 16) ^ sw));
    aq[1] = *(const short8*)((const char*)qs + ((row * 128 + 64 + kg * 16) ^ sw));
  }
  f32x4 s[16] = {};
  #pragma unroll
  for (int j = 0; j < 16; ++j) {
    const int row = j * 16 + lr;
    const int sw = (row & 7) << 4;
    const short8 b0 = *(const short8*)((const char*)us + ((row * 128 +  0 + kg * 16) ^ sw));
    const short8 b1 = *(const short8*)((const char*)us + ((row * 128 + 64 + kg * 16) ^ sw));
    s[j] = __builtin_amdgcn_mfma_f32_16x16x32_bf16(aq[0], b0, s[j], 0, 0, 0);
    s[j] = __builtin_amdgcn_mfma_f32_16x16x32_bf16(aq[1], b1, s[j], 0, 0, 0);
  }

  // ---- softmax over p (256) per q-row; row q = w*16 + kg*4 + r ----
  float inv_[4];
  #pragma unroll
  for (int j = 0; j < 16; ++j)
    #pragma unroll
    for (int r = 0; r < 4; ++r) s[j][r] *= tv;
  #pragma unroll
  for (int r = 0; r < 4; ++r) {
    float m = s[0][r];
    #pragma unroll
    for (int j = 1; j < 16; ++j) m = fmaxf(m, s[j][r]);
    #pragma unroll
    for (int off = 1; off < 16; off <<= 1) m = fmaxf(m, __shfl_xor(m, off));
    float sum = 0.f;
    #pragma unroll
    for (int j = 0; j < 16; ++j) { s[j][r] = __expf(s[j][r] - m); sum += s[j][r]; }
    #pragma unroll
    for (int off = 1; off < 16; off <<= 1) sum += __shfl_xor(sum, off);
    inv_[r] = 1.0f / sum;
  }
  __syncthreads();   // all waves done reading kpT from us

  // ---- write P (bf16) into us as [q 64][p 256], swizzled ----
  #pragma unroll
  for (int r = 0; r < 4; ++r) {
    const int q = w * 16 + kg * 4 + r;
    const int sw = (q & 7) << 4;
    #pragma unroll
    for (int j = 0; j < 16; ++j) {
      const int p = j * 16 + lr;
      ((unsigned short*)us)[((q * 512 + p * 2) ^ sw) >> 1] = f2bfu(s[j][r] * inv_[r]);
    }
  }
  __syncthreads();

  // ---- PV-phase: O^T = vp @ P^T  (A = vp d-rows, B = P q-rows) ----
  f32x4 o[4] = {};
  #pragma unroll
  for (int kc = 0; kc < 8; ++kc) {
    const int qrow = w * 16 + lr;
    const short8 pb = *(const short8*)((const char*)us +
        ((qrow * 512 + kc * 64 + kg * 16) ^ ((qrow & 7) << 4)));
    #pragma unroll
    for (int i = 0; i < 4; ++i) {
      const int drow = i * 16 + lr;
      const short8 vb = *(const short8*)((const char*)vs +
          ((drow * 512 + kc * 64 + kg * 16) ^ ((drow & 7) << 4)));
      o[i] = __builtin_amdgcn_mfma_f32_16x16x32_bf16(vb, pb, o[i], 0, 0, 0);
    }
  }
  // D[m=d][n=q]: q = w*16 + lr, d = i*16 + kg*4 + r.
  // Transposed store: xatT[(bh*64 + d)*4096 + q].
  const int qq = q0 + w * 16 + lr;
  bf16* ob = xatT + (size_t)bh * (HD_ * (size_t)N1_) + qq;
  #pragma unroll
  for (int i = 0; i < 4; ++i)
    #pragma unroll
    for (int r = 0; r < 4; ++r) {
      const int d = i * 16 + kg * 4 + r;
      ob[(size_t)d * N1_] = f2bf(o[i][r]);
    }
}

// ---------------------------------------------------------------------------
// x = l2norm(scramble(attn) + q_skip). With xatT[b,h,d,q] the gather for
// output row n=(d,h,qhi) column c is CONTIGUOUS: xatT[bh][d][qhi*512 + c].
__global__ __launch_bounds__(256) void norm1_kernel(
    const bf16* __restrict__ xatT, const bf16* __restrict__ qb,
    bf16* __restrict__ xb)
{
  const int row = blockIdx.x;                  // b*4096 + n
  const int b = row >> 12, np = row & 4095;
  const int d = np >> 6, h = (np >> 3) & 7, qhi = np & 7;
  const int c = threadIdx.x * 2;
  const size_t tbase = ((size_t)(b * H_ + h) * HD_ + d) * N1_ + qhi * 512 + c;
  const size_t qbase = (size_t)row * C_ + c;
  const ushort2 xa = *(const ushort2*)((const unsigned short*)xatT + tbase);
  const ushort2 qa = *(const ushort2*)((const unsigned short*)qb + qbase);
  float v0 = ubf2f(xa.x) + ubf2f(qa.x);
  float v1 = ubf2f(xa.y) + ubf2f(qa.y);
  float ss = v0 * v0 + v1 * v1;
  #pragma unroll
  for (int off = 32; off > 0; off >>= 1) ss += __shfl_xor(ss, off);
  __shared__ float sw[4];
  if ((threadIdx.x & 63) == 0) sw[threadIdx.x >> 6] = ss;
  __syncthreads();
  const float tot = sw[0] + sw[1] + sw[2] + sw[3];
  const float scale = 1.0f / fmaxf(sqrtf(tot), 1e-12f);
  ushort2 o;
  o.x = f2bfu(v0 * scale);
  o.y = f2bfu(v1 * scale);
  *(ushort2*)((unsigned short*)xb + qbase) = o;
}

__global__ __launch_bounds__(256) void norm2_kernel(
    const float* __restrict__ yb, const bf16* __restrict__ xb,
    float* __restrict__ outp)
{
  const int row = blockIdx.x;
  const int c0 = threadIdx.x, c1 = threadIdx.x + 256;
  float v0 = yb[(size_t)row * C_ + c0] + bf2f(xb[(size_t)row * C_ + c0]);
  float v1 = yb[(size_t)row * C_ + c1] + bf2f(xb[(size_t)row * C_ + c1]);
  float ss = v0 * v0 + v1 * v1;
  #pragma unroll
  for (int off = 32; off > 0; off >>= 1) ss += __shfl_xor(ss, off);
  __shared__ float sw[4];
  if ((threadIdx.x & 63) == 0) sw[threadIdx.x >> 6] = ss;
  __syncthreads();
  const float tot = sw[0] + sw[1] + sw[2] + sw[3];
  const float scale = 1.0f / fmaxf(sqrtf(tot), 1e-12f);
  outp[(size_t)row * C_ + c0] = v0 * scale;
  outp[(size_t)row * C_ + c1] = v1 * scale;
}

// ---------------------------------------------------------------------------
extern "C" void kernel_launch(void* const* d_in, const int* in_sizes, int n_in,
                              void* d_out, int out_size, void* d_ws, size_t ws_size,
                              hipStream_t stream)
{
  const float* x1   = (const float*)d_in[0];
  const float* x2   = (const float*)d_in[1];
  const float* Wq   = (const float*)d_in[2];
  const float* bq   = (const float*)d_in[3];
  const float* Wkv  = (const float*)d_in[4];
  const float* bkv  = (const float*)d_in[5];
  const float* Wp   = (const float*)d_in[6];
  const float* bp   = (const float*)d_in[7];
  const float* posq = (const float*)d_in[8];
  const float* posk = (const float*)d_in[9];
  const float* temp = (const float*)d_in[10];
  const float* W1   = (const float*)d_in[11];
  const float* b1   = (const float*)d_in[12];
  const float* W2   = (const float*)d_in[13];
  const float* b2   = (const float*)d_in[14];

  // Workspace layout (base, pre-MLP):
  //  A [0,32M):      x2b -> x1b -> xb
  //  B [32,64M):     xatT -> hb(start)          (k/v natural never materialized)
  //  C [64,96M):     kT -> vT -> qb             (written directly by TRANSC GEMMs)
  //  [96,98M):       kpT        (dead after attn)
  //  [98,100M):      vp         (dead after attn)
  //  [100,102M):     WpT        (dead after proj)
  //  [102M..):       Wqt/Wkt/Wvt (dead after q/k/v gemms)
  char* ws = (char*)d_ws;
  bf16*  Abuf = (bf16*)(ws);
  bf16*  Bbuf = (bf16*)(ws + 33554432);
  bf16*  Cbuf = (bf16*)(ws + 67108864);
  bf16*  kpT  = (bf16*)(ws + 100663296);
  bf16*  vpb  = (bf16*)(ws + 102760448);
  bf16*  WpT  = (bf16*)(ws + 104857600);
  bf16*  Wqt  = (bf16*)(ws + 106954752);
  bf16*  Wkt  = (bf16*)(ws + 107479040);
  bf16*  Wvt  = (bf16*)(ws + 108003328);
  float* outp = (float*)d_out;

  // MLP chunk size selected by available workspace (largest that fits).
  int CH;
  size_t w1t_off, w2t_off, yb_off;
  if (ws_size >= 239075328UL) {            // 228 MiB: single pass
    CH = 32768; w1t_off = 167772160UL; w2t_off = 169869312UL; yb_off = 171966464UL;
  } else if (ws_size >= 138412032UL) {     // 132 MiB: 2 chunks
    CH = 16384; w1t_off = 100663296UL; w2t_off = 102760448UL; yb_off = 104857600UL;
  } else {                                 // known-good 4-chunk layout
    CH = 8192;  w1t_off = 100663296UL; w2t_off = 102760448UL; yb_off = 106954752UL;
  }
  bf16*  W1t = (bf16*)(ws + w1t_off);
  bf16*  W2t = (bf16*)(ws + w2t_off);
  float* yb  = (float*)(ws + yb_off);

  const dim3 blk(256);
  const int Mrows = B_ * N1_;       // 32768
  bf16* xatT = Bbuf;
  bf16* xb   = Abuf;
  bf16* hb   = Bbuf;
  bf16* qb   = Cbuf;

  // x2 -> bf16
  f2b_kernel<<<dim3(2048), blk, 0, stream>>>(x2, Abuf, (B_ * N2_ * C_) / 4);
  // weight transposes: f32 (K,N) -> bf16 (N,K)
  transpose_f2b_kernel<<<dim3(16, 16), blk, 0, stream>>>(Wkv,      Wkt, C_, C_, 2 * C_);
  transpose_f2b_kernel<<<dim3(16, 16), blk, 0, stream>>>(Wkv + C_, Wvt, C_, C_, 2 * C_);
  transpose_f2b_kernel<<<dim3(16, 16), blk, 0, stream>>>(Wq,       Wqt, C_, C_, C_);
  transpose_f2b_kernel<<<dim3(8, 128), blk, 0, stream>>>(Wp,       WpT, N2_, P_, P_);

  // kT[b,c,n] = (x2@Wkv[:, :C] + bkv[:C] + pos_k)^T  -> C (TRANSC epilogue)
  mfma_gemm_kernel<128,0,0,1,1><<<dim3(C_/128, Mrows/128), blk, 0, stream>>>(
      Abuf, Wkt, bkv, posk, N2_ - 1, Cbuf, Mrows, C_, C_);
  // kpT[b,h,p,d] = WpT @ kT[b,h]^T + bp (row-bias)
  proj_kernel<1><<<dim3(1, 4, B_*H_), blk, 0, stream>>>(
      WpT, Cbuf, bp, kpT, P_, HD_, N2_, 0L, (long)HD_*N2_, (long)P_*HD_);
  // vT[b,c,n] = (x2@Wkv[:, C:] + bkv[C:])^T  -> C (kT dead)
  mfma_gemm_kernel<128,0,0,0,1><<<dim3(C_/128, Mrows/128), blk, 0, stream>>>(
      Abuf, Wvt, bkv + C_, nullptr, 0, Cbuf, Mrows, C_, C_);
  // vp[b,h,d,p] = vT[b,h] @ WpT^T + bp (col-bias)
  proj_kernel<0><<<dim3(4, 1, B_*H_), blk, 0, stream>>>(
      Cbuf, WpT, bp, vpb, HD_, P_, N2_, (long)HD_*N2_, 0L, (long)HD_*P_);
  // x1 -> bf16 (x2b dead)
  f2b_kernel<<<dim3(2048), blk, 0, stream>>>(x1, Abuf, (B_ * N1_ * C_) / 4);
  // q = x1@Wq + bq + pos_q  -> C (vT dead)
  mfma_gemm_kernel<128,0,0,1,0><<<dim3(C_/128, Mrows/128), blk, 0, stream>>>(
      Abuf, Wqt, bq, posq, N1_ - 1, qb, Mrows, C_, C_);
  // MFMA attention -> xatT[b,h,d,q] (region B)
  attn_mfma_kernel<<<dim3(N1_/64, H_, B_), blk, 0, stream>>>(
      qb, kpT, vpb, temp, xatT);
  // MLP weight transposes (kpT/vp dead)
  transpose_f2b_kernel<<<dim3(64, 16), blk, 0, stream>>>(W1, W1t, C_,   MLP_, MLP_);
  transpose_f2b_kernel<<<dim3(16, 64), blk, 0, stream>>>(W2, W2t, MLP_, C_,   C_);
  // x = l2norm(scramble(attn) + q) -> region A (x1b dead)
  norm1_kernel<<<dim3(Mrows), blk, 0, stream>>>(xatT, qb, xb);
  // MLP + final norm, chunked (CH rows per chunk)
  for (int c = 0; c < Mrows / CH; ++c) {
    const bf16* xc = xb + (size_t)c * CH * C_;
    mfma_gemm_kernel<128,0,1,0,0><<<dim3(MLP_/128, CH/128), blk, 0, stream>>>(
        xc, W1t, b1, nullptr, 0, hb, CH, MLP_, C_);
    mfma_gemm_kernel<128,1,0,0,0><<<dim3(C_/128, CH/128), blk, 0, stream>>>(
        hb, W2t, b2, nullptr, 0, yb, CH, C_, MLP_);
    norm2_kernel<<<dim3(CH), blk, 0, stream>>>(
        yb, xc, outp + (size_t)c * CH * C_);
  }
}